// Round 2
// baseline (662.325 us; speedup 1.0000x reference)
//
#include <hip/hip_runtime.h>

#define IN_DIM 128
#define HID 64

// ---------------- degree count ----------------
__global__ void k_count(const int* __restrict__ dst, int E, int* __restrict__ deg) {
    int e = blockIdx.x * blockDim.x + threadIdx.x;
    if (e < E) atomicAdd(&deg[dst[e]], 1);
}

// ---------------- exclusive scan (single block, 2-level) + dis = rsqrt(deg+1) ----------------
__global__ __launch_bounds__(1024) void k_scan(const int* __restrict__ deg, int N,
                                               int* __restrict__ row_start,
                                               float* __restrict__ dis) {
    __shared__ int wsum[16];
    int tid = threadIdx.x;
    int per = (N + 1023) >> 10;
    int b = tid * per;
    int e = min(N, b + per);
    int s = 0;
    for (int i = b; i < e; ++i) s += deg[i];
    int lane = tid & 63, wid = tid >> 6;
    // wave inclusive scan
    int v = s;
    for (int off = 1; off < 64; off <<= 1) {
        int t = __shfl_up(v, off);
        if (lane >= off) v += t;
    }
    if (lane == 63) wsum[wid] = v;
    __syncthreads();
    if (wid == 0) {
        int w = (lane < 16) ? wsum[lane] : 0;
        for (int off = 1; off < 16; off <<= 1) {
            int t = __shfl_up(w, off);
            if (lane >= off) w += t;
        }
        if (lane < 16) wsum[lane] = w;
    }
    __syncthreads();
    int base = (wid > 0 ? wsum[wid - 1] : 0) + (v - s);  // exclusive prefix of this thread
    int run = base;
    for (int i = b; i < e; ++i) {
        int d = deg[i];
        row_start[i] = run;
        dis[i] = rsqrtf((float)(d + 1));
        run += d;
    }
    if (tid == 1023) row_start[N] = run;
}

// ---------------- CSR fill (counting sort by dst) ----------------
__global__ void k_fill(const int* __restrict__ src, const int* __restrict__ dst, int E,
                       const int* __restrict__ row_start, int* __restrict__ cursor,
                       int* __restrict__ csr_src) {
    int e = blockIdx.x * blockDim.x + threadIdx.x;
    if (e < E) {
        int d = dst[e];
        int pos = atomicAdd(&cursor[d], 1);
        csr_src[row_start[d] + pos] = src[e];
    }
}

// ---------------- tiled GEMM: out[r][c] = dis[r] * sum_k X[r][k]*W[k][c]  (64 cols) ----------------
template <int K>
__global__ __launch_bounds__(256) void k_gemm_scale(const float* __restrict__ X,
                                                    const float* __restrict__ W,
                                                    const float* __restrict__ dis, int N,
                                                    float* __restrict__ out) {
    constexpr int KP = K + 4;  // padded float stride for X tile
    constexpr int KC = K / 4;  // float4 per row
    __shared__ float Xs[64 * KP];
    __shared__ float Ws[K * 64];
    int tid = threadIdx.x;
    int row0 = blockIdx.x * 64;

    // stage W (K*16 float4)
    const float4* Wg = (const float4*)W;
    float4* Ws4 = (float4*)Ws;
    for (int i = tid; i < K * 16; i += 256) Ws4[i] = Wg[i];
    // stage X rows row0..row0+63 (coalesced float4)
    const float4* Xg = (const float4*)X;
    for (int c = tid; c < 64 * KC; c += 256) {
        int r = c / KC, k4 = c % KC;
        int row = row0 + r;
        float4 vv = make_float4(0.f, 0.f, 0.f, 0.f);
        if (row < N) vv = Xg[(size_t)row * KC + k4];
        *(float4*)&Xs[r * KP + k4 * 4] = vv;
    }
    __syncthreads();

    int cg = tid & 15;   // col group: cols cg*4..cg*4+3
    int rg = tid >> 4;   // row group: rows rg*4..rg*4+3
    float acc[4][4] = {};
#pragma unroll
    for (int k = 0; k < K; k += 4) {
        float4 w0 = *(float4*)&Ws[(k + 0) * 64 + cg * 4];
        float4 w1 = *(float4*)&Ws[(k + 1) * 64 + cg * 4];
        float4 w2 = *(float4*)&Ws[(k + 2) * 64 + cg * 4];
        float4 w3 = *(float4*)&Ws[(k + 3) * 64 + cg * 4];
#pragma unroll
        for (int i = 0; i < 4; ++i) {
            float4 xv = *(float4*)&Xs[(rg * 4 + i) * KP + k];
            acc[i][0] += xv.x * w0.x + xv.y * w1.x + xv.z * w2.x + xv.w * w3.x;
            acc[i][1] += xv.x * w0.y + xv.y * w1.y + xv.z * w2.y + xv.w * w3.y;
            acc[i][2] += xv.x * w0.z + xv.y * w1.z + xv.z * w2.z + xv.w * w3.z;
            acc[i][3] += xv.x * w0.w + xv.y * w1.w + xv.z * w2.w + xv.w * w3.w;
        }
    }
#pragma unroll
    for (int i = 0; i < 4; ++i) {
        int row = row0 + rg * 4 + i;
        if (row < N) {
            float s = dis[row];
            *(float4*)&out[(size_t)row * 64 + cg * 4] =
                make_float4(acc[i][0] * s, acc[i][1] * s, acc[i][2] * s, acc[i][3] * s);
        }
    }
}

// ---------------- gather-aggregate: h = relu(dis[i]*(Hs[i] + sum Hs[src]) + b) ----------------
__global__ __launch_bounds__(256) void k_aggregate(const float* __restrict__ Hs,
                                                   const int* __restrict__ row_start,
                                                   const int* __restrict__ csr_src,
                                                   const float* __restrict__ dis,
                                                   const float* __restrict__ bias, int N,
                                                   float* __restrict__ out) {
    int wave = threadIdx.x >> 6, lane = threadIdx.x & 63;
    int node = blockIdx.x * 4 + wave;
    if (node >= N) return;
    float acc = Hs[(size_t)node * HID + lane];  // self loop
    int e0 = row_start[node], e1 = row_start[node + 1];
    for (int eb = e0; eb < e1; eb += 64) {
        int cnt = min(64, e1 - eb);
        int sv = (eb + lane < e1) ? csr_src[eb + lane] : 0;
        for (int j = 0; j < cnt; ++j) {
            int s = __shfl(sv, j);
            acc += Hs[(size_t)s * HID + lane];
        }
    }
    float v = fmaxf(acc * dis[node] + bias[lane], 0.f);
    out[(size_t)node * HID + lane] = v;
}

// ---------------- aggregate + fused head: logits = relu(agg) @ Wl + bl ----------------
__global__ __launch_bounds__(256) void k_aggregate_head(const float* __restrict__ Hs,
                                                        const int* __restrict__ row_start,
                                                        const int* __restrict__ csr_src,
                                                        const float* __restrict__ dis,
                                                        const float* __restrict__ bias,
                                                        const float* __restrict__ Wl,
                                                        const float* __restrict__ bl, int N,
                                                        float* __restrict__ out) {
    int wave = threadIdx.x >> 6, lane = threadIdx.x & 63;
    int node = blockIdx.x * 4 + wave;
    if (node >= N) return;
    float acc = Hs[(size_t)node * HID + lane];
    int e0 = row_start[node], e1 = row_start[node + 1];
    for (int eb = e0; eb < e1; eb += 64) {
        int cnt = min(64, e1 - eb);
        int sv = (eb + lane < e1) ? csr_src[eb + lane] : 0;
        for (int j = 0; j < cnt; ++j) {
            int s = __shfl(sv, j);
            acc += Hs[(size_t)s * HID + lane];
        }
    }
    float v = fmaxf(acc * dis[node] + bias[lane], 0.f);
    float a0 = v * Wl[lane * 2 + 0];
    float a1 = v * Wl[lane * 2 + 1];
    for (int off = 32; off; off >>= 1) {
        a0 += __shfl_down(a0, off);
        a1 += __shfl_down(a1, off);
    }
    if (lane == 0) {
        out[node * 2 + 0] = a0 + bl[0];
        out[node * 2 + 1] = a1 + bl[1];
    }
}

extern "C" void kernel_launch(void* const* d_in, const int* in_sizes, int n_in,
                              void* d_out, int out_size, void* d_ws, size_t ws_size,
                              hipStream_t stream) {
    const float* x  = (const float*)d_in[0];
    const int*   ei = (const int*)d_in[1];
    const float* W1 = (const float*)d_in[2];
    const float* b1 = (const float*)d_in[3];
    const float* W2 = (const float*)d_in[4];
    const float* b2 = (const float*)d_in[5];
    const float* Wl = (const float*)d_in[6];
    const float* bl = (const float*)d_in[7];

    const int N = in_sizes[0] / IN_DIM;   // 50000
    const int E = in_sizes[1] / 2;        // 800000
    const int* src = ei;
    const int* dst = ei + E;

    char* ws = (char*)d_ws;
    size_t off = 0;
    auto alloc = [&](size_t bytes) -> void* {
        void* p = ws + off;
        off = (off + bytes + 255) & ~(size_t)255;
        return p;
    };
    int*   deg       = (int*)alloc((size_t)N * 4);
    int*   row_start = (int*)alloc(((size_t)N + 1) * 4);
    int*   cursor    = (int*)alloc((size_t)N * 4);
    int*   csr_src   = (int*)alloc((size_t)E * 4);
    float* dis       = (float*)alloc((size_t)N * 4);
    float* bufA      = (float*)alloc((size_t)N * HID * 4);  // Hs
    float* bufB      = (float*)alloc((size_t)N * HID * 4);  // h

    hipMemsetAsync(deg, 0, (size_t)N * 4, stream);
    hipMemsetAsync(cursor, 0, (size_t)N * 4, stream);

    k_count<<<(E + 255) / 256, 256, 0, stream>>>(dst, E, deg);
    k_scan<<<1, 1024, 0, stream>>>(deg, N, row_start, dis);
    k_fill<<<(E + 255) / 256, 256, 0, stream>>>(src, dst, E, row_start, cursor, csr_src);

    int gblk = (N + 63) / 64;
    int nblk = (N + 3) / 4;
    // layer 1
    k_gemm_scale<IN_DIM><<<gblk, 256, 0, stream>>>(x, W1, dis, N, bufA);
    k_aggregate<<<nblk, 256, 0, stream>>>(bufA, row_start, csr_src, dis, b1, N, bufB);
    // layer 2
    k_gemm_scale<HID><<<gblk, 256, 0, stream>>>(bufB, W2, dis, N, bufA);
    k_aggregate_head<<<nblk, 256, 0, stream>>>(bufA, row_start, csr_src, dis, b2, Wl, bl, N,
                                               (float*)d_out);
}

// Round 3
// 341.127 us; speedup vs baseline: 1.9416x; 1.9416x over previous
//
#include <hip/hip_runtime.h>

#define IN_DIM 128
#define HID 64

// ---------------- degree count ----------------
__global__ void k_count(const int* __restrict__ dst, int E, int* __restrict__ deg) {
    int e = blockIdx.x * blockDim.x + threadIdx.x;
    if (e < E) atomicAdd(&deg[dst[e]], 1);
}

// ---------------- exclusive scan (single block, 2-level) + dis = rsqrt(deg+1) ----------------
__global__ __launch_bounds__(1024) void k_scan(const int* __restrict__ deg, int N,
                                               int* __restrict__ row_start,
                                               float* __restrict__ dis) {
    __shared__ int wsum[16];
    int tid = threadIdx.x;
    int per = (N + 1023) >> 10;
    int b = tid * per;
    int e = min(N, b + per);
    int s = 0;
    for (int i = b; i < e; ++i) s += deg[i];
    int lane = tid & 63, wid = tid >> 6;
    int v = s;
    for (int off = 1; off < 64; off <<= 1) {
        int t = __shfl_up(v, off);
        if (lane >= off) v += t;
    }
    if (lane == 63) wsum[wid] = v;
    __syncthreads();
    if (wid == 0) {
        int w = (lane < 16) ? wsum[lane] : 0;
        for (int off = 1; off < 16; off <<= 1) {
            int t = __shfl_up(w, off);
            if (lane >= off) w += t;
        }
        if (lane < 16) wsum[lane] = w;
    }
    __syncthreads();
    int base = (wid > 0 ? wsum[wid - 1] : 0) + (v - s);
    int run = base;
    for (int i = b; i < e; ++i) {
        int d = deg[i];
        row_start[i] = run;
        dis[i] = rsqrtf((float)(d + 1));
        run += d;
    }
    if (tid == 1023) row_start[N] = run;
}

// ---------------- CSR fill (counting sort by dst) ----------------
__global__ void k_fill(const int* __restrict__ src, const int* __restrict__ dst, int E,
                       const int* __restrict__ row_start, int* __restrict__ cursor,
                       int* __restrict__ csr_src) {
    int e = blockIdx.x * blockDim.x + threadIdx.x;
    if (e < E) {
        int d = dst[e];
        int pos = atomicAdd(&cursor[d], 1);
        csr_src[row_start[d] + pos] = src[e];
    }
}

// ---------------- tiled GEMM: out[r][c] = dis[r] * sum_k X[r][k]*W[k][c]  (64 cols) ----------------
template <int K>
__global__ __launch_bounds__(256) void k_gemm_scale(const float* __restrict__ X,
                                                    const float* __restrict__ W,
                                                    const float* __restrict__ dis, int N,
                                                    float* __restrict__ out) {
    constexpr int KP = K + 4;
    constexpr int KC = K / 4;
    __shared__ float Xs[64 * KP];
    __shared__ float Ws[K * 64];
    int tid = threadIdx.x;
    int row0 = blockIdx.x * 64;

    const float4* Wg = (const float4*)W;
    float4* Ws4 = (float4*)Ws;
    for (int i = tid; i < K * 16; i += 256) Ws4[i] = Wg[i];
    const float4* Xg = (const float4*)X;
    for (int c = tid; c < 64 * KC; c += 256) {
        int r = c / KC, k4 = c % KC;
        int row = row0 + r;
        float4 vv = make_float4(0.f, 0.f, 0.f, 0.f);
        if (row < N) vv = Xg[(size_t)row * KC + k4];
        *(float4*)&Xs[r * KP + k4 * 4] = vv;
    }
    __syncthreads();

    int cg = tid & 15;
    int rg = tid >> 4;
    float acc[4][4] = {};
#pragma unroll 2
    for (int k = 0; k < K; k += 4) {
        float4 w0 = *(float4*)&Ws[(k + 0) * 64 + cg * 4];
        float4 w1 = *(float4*)&Ws[(k + 1) * 64 + cg * 4];
        float4 w2 = *(float4*)&Ws[(k + 2) * 64 + cg * 4];
        float4 w3 = *(float4*)&Ws[(k + 3) * 64 + cg * 4];
#pragma unroll
        for (int i = 0; i < 4; ++i) {
            float4 xv = *(float4*)&Xs[(rg * 4 + i) * KP + k];
            acc[i][0] += xv.x * w0.x + xv.y * w1.x + xv.z * w2.x + xv.w * w3.x;
            acc[i][1] += xv.x * w0.y + xv.y * w1.y + xv.z * w2.y + xv.w * w3.y;
            acc[i][2] += xv.x * w0.z + xv.y * w1.z + xv.z * w2.z + xv.w * w3.z;
            acc[i][3] += xv.x * w0.w + xv.y * w1.w + xv.z * w2.w + xv.w * w3.w;
        }
    }
#pragma unroll
    for (int i = 0; i < 4; ++i) {
        int row = row0 + rg * 4 + i;
        if (row < N) {
            float s = dis[row];
            *(float4*)&out[(size_t)row * 64 + cg * 4] =
                make_float4(acc[i][0] * s, acc[i][1] * s, acc[i][2] * s, acc[i][3] * s);
        }
    }
}

// ---------------- gather-aggregate: h = relu(dis[i]*(Hs[i] + sum Hs[src]) + b) ----------------
__global__ __launch_bounds__(256) void k_aggregate(const float* __restrict__ Hs,
                                                   const int* __restrict__ row_start,
                                                   const int* __restrict__ csr_src,
                                                   const float* __restrict__ dis,
                                                   const float* __restrict__ bias, int N,
                                                   float* __restrict__ out) {
    int wave = threadIdx.x >> 6, lane = threadIdx.x & 63;
    int node = blockIdx.x * 4 + wave;
    if (node >= N) return;
    float acc = Hs[(size_t)node * HID + lane];
    int e0 = row_start[node], e1 = row_start[node + 1];
    for (int eb = e0; eb < e1; eb += 64) {
        int cnt = min(64, e1 - eb);
        int sv = (eb + lane < e1) ? csr_src[eb + lane] : 0;
        for (int j = 0; j < cnt; ++j) {
            int s = __shfl(sv, j);
            acc += Hs[(size_t)s * HID + lane];
        }
    }
    float v = fmaxf(acc * dis[node] + bias[lane], 0.f);
    out[(size_t)node * HID + lane] = v;
}

// ---------------- aggregate + fused head: logits = relu(agg) @ Wl + bl ----------------
__global__ __launch_bounds__(256) void k_aggregate_head(const float* __restrict__ Hs,
                                                        const int* __restrict__ row_start,
                                                        const int* __restrict__ csr_src,
                                                        const float* __restrict__ dis,
                                                        const float* __restrict__ bias,
                                                        const float* __restrict__ Wl,
                                                        const float* __restrict__ bl, int N,
                                                        float* __restrict__ out) {
    int wave = threadIdx.x >> 6, lane = threadIdx.x & 63;
    int node = blockIdx.x * 4 + wave;
    if (node >= N) return;
    float acc = Hs[(size_t)node * HID + lane];
    int e0 = row_start[node], e1 = row_start[node + 1];
    for (int eb = e0; eb < e1; eb += 64) {
        int cnt = min(64, e1 - eb);
        int sv = (eb + lane < e1) ? csr_src[eb + lane] : 0;
        for (int j = 0; j < cnt; ++j) {
            int s = __shfl(sv, j);
            acc += Hs[(size_t)s * HID + lane];
        }
    }
    float v = fmaxf(acc * dis[node] + bias[lane], 0.f);
    float a0 = v * Wl[lane * 2 + 0];
    float a1 = v * Wl[lane * 2 + 1];
    for (int off = 32; off; off >>= 1) {
        a0 += __shfl_down(a0, off);
        a1 += __shfl_down(a1, off);
    }
    if (lane == 0) {
        out[node * 2 + 0] = a0 + bl[0];
        out[node * 2 + 1] = a1 + bl[1];
    }
}

extern "C" void kernel_launch(void* const* d_in, const int* in_sizes, int n_in,
                              void* d_out, int out_size, void* d_ws, size_t ws_size,
                              hipStream_t stream) {
    const float* x  = (const float*)d_in[0];
    const int*   ei = (const int*)d_in[1];
    const float* W1 = (const float*)d_in[2];
    const float* b1 = (const float*)d_in[3];
    const float* W2 = (const float*)d_in[4];
    const float* b2 = (const float*)d_in[5];
    const float* Wl = (const float*)d_in[6];
    const float* bl = (const float*)d_in[7];

    const int N = in_sizes[0] / IN_DIM;   // 50000
    const int E = in_sizes[1] / 2;        // 800000
    const int* src = ei;
    const int* dst = ei + E;

    char* ws = (char*)d_ws;
    size_t off = 0;
    auto alloc = [&](size_t bytes) -> void* {
        void* p = ws + off;
        off = (off + bytes + 255) & ~(size_t)255;
        return p;
    };
    int*   deg       = (int*)alloc((size_t)N * 4);
    int*   row_start = (int*)alloc(((size_t)N + 1) * 4);
    int*   cursor    = (int*)alloc((size_t)N * 4);
    int*   csr_src   = (int*)alloc((size_t)E * 4);
    float* dis       = (float*)alloc((size_t)N * 4);
    float* bufA      = (float*)alloc((size_t)N * HID * 4);
    float* bufB      = (float*)alloc((size_t)N * HID * 4);

    hipMemsetAsync(deg, 0, (size_t)N * 4, stream);
    hipMemsetAsync(cursor, 0, (size_t)N * 4, stream);

    k_count<<<(E + 255) / 256, 256, 0, stream>>>(dst, E, deg);
    k_scan<<<1, 1024, 0, stream>>>(deg, N, row_start, dis);
    k_fill<<<(E + 255) / 256, 256, 0, stream>>>(src, dst, E, row_start, cursor, csr_src);

    int gblk = (N + 63) / 64;
    int nblk = (N + 3) / 4;
    k_gemm_scale<IN_DIM><<<gblk, 256, 0, stream>>>(x, W1, dis, N, bufA);
    k_aggregate<<<nblk, 256, 0, stream>>>(bufA, row_start, csr_src, dis, b1, N, bufB);
    k_gemm_scale<HID><<<gblk, 256, 0, stream>>>(bufB, W2, dis, N, bufA);
    k_aggregate_head<<<nblk, 256, 0, stream>>>(bufA, row_start, csr_src, dis, b2, Wl, bl, N,
                                               (float*)d_out);
}

// Round 4
// 242.834 us; speedup vs baseline: 2.7275x; 1.4048x over previous
//
#include <hip/hip_runtime.h>

#define IN_DIM 128
#define HID 64

// ---------------- degree count ----------------
__global__ void k_count(const int* __restrict__ dst, int E, int* __restrict__ deg) {
    int e = blockIdx.x * blockDim.x + threadIdx.x;
    if (e < E) atomicAdd(&deg[dst[e]], 1);
}

// ---------------- 3-phase scan ----------------
// phase A: per-block sums of deg
__global__ __launch_bounds__(256) void k_scan_part(const int* __restrict__ deg, int N,
                                                   int* __restrict__ bsum) {
    int tid = threadIdx.x;
    int i = blockIdx.x * 256 + tid;
    int v = (i < N) ? deg[i] : 0;
    int lane = tid & 63, wid = tid >> 6;
    for (int off = 32; off; off >>= 1) v += __shfl_down(v, off);
    __shared__ int ws[4];
    if (lane == 0) ws[wid] = v;
    __syncthreads();
    if (tid == 0) bsum[blockIdx.x] = ws[0] + ws[1] + ws[2] + ws[3];
}

// phase B: exclusive scan of bsum (nb <= 256), also writes row_start[N] = total
__global__ __launch_bounds__(256) void k_scan_top(int* __restrict__ bsum, int nb,
                                                  int* __restrict__ row_start, int N) {
    int tid = threadIdx.x;
    int lane = tid & 63, wid = tid >> 6;
    int v = (tid < nb) ? bsum[tid] : 0;
    int orig = v;
    for (int off = 1; off < 64; off <<= 1) {
        int t = __shfl_up(v, off);
        if (lane >= off) v += t;
    }
    __shared__ int ws[4];
    if (lane == 63) ws[wid] = v;
    __syncthreads();
    int woff = 0;
    for (int w = 0; w < 4; ++w)
        if (w < wid) woff += ws[w];
    if (tid < nb) bsum[tid] = woff + v - orig;  // exclusive
    if (tid == 0) row_start[N] = ws[0] + ws[1] + ws[2] + ws[3];
}

// phase C: per-element exclusive scan + dis = rsqrt(deg+1)
__global__ __launch_bounds__(256) void k_scan_final(const int* __restrict__ deg,
                                                    const int* __restrict__ bsum, int N,
                                                    int* __restrict__ row_start,
                                                    float* __restrict__ dis) {
    int tid = threadIdx.x;
    int i = blockIdx.x * 256 + tid;
    int v = (i < N) ? deg[i] : 0;
    int orig = v;
    int lane = tid & 63, wid = tid >> 6;
    for (int off = 1; off < 64; off <<= 1) {
        int t = __shfl_up(v, off);
        if (lane >= off) v += t;
    }
    __shared__ int ws[4];
    if (lane == 63) ws[wid] = v;
    __syncthreads();
    int woff = 0;
    for (int w = 0; w < 4; ++w)
        if (w < wid) woff += ws[w];
    if (i < N) {
        row_start[i] = bsum[blockIdx.x] + woff + v - orig;
        dis[i] = rsqrtf((float)(orig + 1));
    }
}

// ---------------- CSR fill (counting sort by dst) ----------------
__global__ void k_fill(const int* __restrict__ src, const int* __restrict__ dst, int E,
                       const int* __restrict__ row_start, int* __restrict__ cursor,
                       int* __restrict__ csr_src) {
    int e = blockIdx.x * blockDim.x + threadIdx.x;
    if (e < E) {
        int d = dst[e];
        int pos = atomicAdd(&cursor[d], 1);
        csr_src[row_start[d] + pos] = src[e];
    }
}

// ---------------- tiled GEMM: out[r][c] = dis[r] * sum_k X[r][k]*W[k][c]  (64 cols) ----------------
template <int K>
__global__ __launch_bounds__(256) void k_gemm_scale(const float* __restrict__ X,
                                                    const float* __restrict__ W,
                                                    const float* __restrict__ dis, int N,
                                                    float* __restrict__ out) {
    constexpr int KP = K + 4;
    constexpr int KC = K / 4;
    __shared__ float Xs[64 * KP];
    __shared__ float Ws[K * 64];
    int tid = threadIdx.x;
    int row0 = blockIdx.x * 64;

    const float4* Wg = (const float4*)W;
    float4* Ws4 = (float4*)Ws;
    for (int i = tid; i < K * 16; i += 256) Ws4[i] = Wg[i];
    const float4* Xg = (const float4*)X;
    for (int c = tid; c < 64 * KC; c += 256) {
        int r = c / KC, k4 = c % KC;
        int row = row0 + r;
        float4 vv = make_float4(0.f, 0.f, 0.f, 0.f);
        if (row < N) vv = Xg[(size_t)row * KC + k4];
        *(float4*)&Xs[r * KP + k4 * 4] = vv;
    }
    __syncthreads();

    int cg = tid & 15;
    int rg = tid >> 4;
    float acc[4][4] = {};
#pragma unroll 2
    for (int k = 0; k < K; k += 4) {
        float4 w0 = *(float4*)&Ws[(k + 0) * 64 + cg * 4];
        float4 w1 = *(float4*)&Ws[(k + 1) * 64 + cg * 4];
        float4 w2 = *(float4*)&Ws[(k + 2) * 64 + cg * 4];
        float4 w3 = *(float4*)&Ws[(k + 3) * 64 + cg * 4];
#pragma unroll
        for (int i = 0; i < 4; ++i) {
            float4 xv = *(float4*)&Xs[(rg * 4 + i) * KP + k];
            acc[i][0] += xv.x * w0.x + xv.y * w1.x + xv.z * w2.x + xv.w * w3.x;
            acc[i][1] += xv.x * w0.y + xv.y * w1.y + xv.z * w2.y + xv.w * w3.y;
            acc[i][2] += xv.x * w0.z + xv.y * w1.z + xv.z * w2.z + xv.w * w3.z;
            acc[i][3] += xv.x * w0.w + xv.y * w1.w + xv.z * w2.w + xv.w * w3.w;
        }
    }
#pragma unroll
    for (int i = 0; i < 4; ++i) {
        int row = row0 + rg * 4 + i;
        if (row < N) {
            float s = dis[row];
            *(float4*)&out[(size_t)row * 64 + cg * 4] =
                make_float4(acc[i][0] * s, acc[i][1] * s, acc[i][2] * s, acc[i][3] * s);
        }
    }
}

// ---------------- gather-aggregate: h = relu(dis[i]*(Hs[i] + sum Hs[src]) + b) ----------------
__global__ __launch_bounds__(256) void k_aggregate(const float* __restrict__ Hs,
                                                   const int* __restrict__ row_start,
                                                   const int* __restrict__ csr_src,
                                                   const float* __restrict__ dis,
                                                   const float* __restrict__ bias, int N,
                                                   float* __restrict__ out) {
    int wave = threadIdx.x >> 6, lane = threadIdx.x & 63;
    int node = blockIdx.x * 4 + wave;
    if (node >= N) return;
    float acc = Hs[(size_t)node * HID + lane];
    int e0 = row_start[node], e1 = row_start[node + 1];
    for (int eb = e0; eb < e1; eb += 64) {
        int cnt = min(64, e1 - eb);
        int sv = (eb + lane < e1) ? csr_src[eb + lane] : 0;
        for (int j = 0; j < cnt; ++j) {
            int s = __shfl(sv, j);
            acc += Hs[(size_t)s * HID + lane];
        }
    }
    float v = fmaxf(acc * dis[node] + bias[lane], 0.f);
    out[(size_t)node * HID + lane] = v;
}

// ---------------- aggregate + fused head: logits = relu(agg) @ Wl + bl ----------------
__global__ __launch_bounds__(256) void k_aggregate_head(const float* __restrict__ Hs,
                                                        const int* __restrict__ row_start,
                                                        const int* __restrict__ csr_src,
                                                        const float* __restrict__ dis,
                                                        const float* __restrict__ bias,
                                                        const float* __restrict__ Wl,
                                                        const float* __restrict__ bl, int N,
                                                        float* __restrict__ out) {
    int wave = threadIdx.x >> 6, lane = threadIdx.x & 63;
    int node = blockIdx.x * 4 + wave;
    if (node >= N) return;
    float acc = Hs[(size_t)node * HID + lane];
    int e0 = row_start[node], e1 = row_start[node + 1];
    for (int eb = e0; eb < e1; eb += 64) {
        int cnt = min(64, e1 - eb);
        int sv = (eb + lane < e1) ? csr_src[eb + lane] : 0;
        for (int j = 0; j < cnt; ++j) {
            int s = __shfl(sv, j);
            acc += Hs[(size_t)s * HID + lane];
        }
    }
    float v = fmaxf(acc * dis[node] + bias[lane], 0.f);
    float a0 = v * Wl[lane * 2 + 0];
    float a1 = v * Wl[lane * 2 + 1];
    for (int off = 32; off; off >>= 1) {
        a0 += __shfl_down(a0, off);
        a1 += __shfl_down(a1, off);
    }
    if (lane == 0) {
        out[node * 2 + 0] = a0 + bl[0];
        out[node * 2 + 1] = a1 + bl[1];
    }
}

extern "C" void kernel_launch(void* const* d_in, const int* in_sizes, int n_in,
                              void* d_out, int out_size, void* d_ws, size_t ws_size,
                              hipStream_t stream) {
    const float* x  = (const float*)d_in[0];
    const int*   ei = (const int*)d_in[1];
    const float* W1 = (const float*)d_in[2];
    const float* b1 = (const float*)d_in[3];
    const float* W2 = (const float*)d_in[4];
    const float* b2 = (const float*)d_in[5];
    const float* Wl = (const float*)d_in[6];
    const float* bl = (const float*)d_in[7];

    const int N = in_sizes[0] / IN_DIM;   // 50000
    const int E = in_sizes[1] / 2;        // 800000
    const int* src = ei;
    const int* dst = ei + E;

    char* ws = (char*)d_ws;
    size_t off = 0;
    auto alloc = [&](size_t bytes) -> void* {
        void* p = ws + off;
        off = (off + bytes + 255) & ~(size_t)255;
        return p;
    };
    int*   deg       = (int*)alloc((size_t)N * 4);
    int*   row_start = (int*)alloc(((size_t)N + 1) * 4);
    int*   cursor    = (int*)alloc((size_t)N * 4);
    int*   csr_src   = (int*)alloc((size_t)E * 4);
    float* dis       = (float*)alloc((size_t)N * 4);
    int*   bsum      = (int*)alloc(1024 * 4);
    float* bufA      = (float*)alloc((size_t)N * HID * 4);
    float* bufB      = (float*)alloc((size_t)N * HID * 4);

    hipMemsetAsync(deg, 0, (size_t)N * 4, stream);
    hipMemsetAsync(cursor, 0, (size_t)N * 4, stream);

    int nb = (N + 255) / 256;  // 196
    k_count<<<(E + 255) / 256, 256, 0, stream>>>(dst, E, deg);
    k_scan_part<<<nb, 256, 0, stream>>>(deg, N, bsum);
    k_scan_top<<<1, 256, 0, stream>>>(bsum, nb, row_start, N);
    k_scan_final<<<nb, 256, 0, stream>>>(deg, bsum, N, row_start, dis);
    k_fill<<<(E + 255) / 256, 256, 0, stream>>>(src, dst, E, row_start, cursor, csr_src);

    int gblk = (N + 63) / 64;
    int nblk = (N + 3) / 4;
    k_gemm_scale<IN_DIM><<<gblk, 256, 0, stream>>>(x, W1, dis, N, bufA);
    k_aggregate<<<nblk, 256, 0, stream>>>(bufA, row_start, csr_src, dis, b1, N, bufB);
    k_gemm_scale<HID><<<gblk, 256, 0, stream>>>(bufB, W2, dis, N, bufA);
    k_aggregate_head<<<nblk, 256, 0, stream>>>(bufA, row_start, csr_src, dis, b2, Wl, bl, N,
                                               (float*)d_out);
}

// Round 5
// 196.364 us; speedup vs baseline: 3.3729x; 1.2366x over previous
//
#include <hip/hip_runtime.h>

#define IN_DIM 128
#define HID 64

// ---------------- degree count ----------------
__global__ void k_count(const int* __restrict__ dst, int E, int* __restrict__ deg) {
    int e = blockIdx.x * blockDim.x + threadIdx.x;
    if (e < E) atomicAdd(&deg[dst[e]], 1);
}

// ---------------- 3-phase scan ----------------
__global__ __launch_bounds__(256) void k_scan_part(const int* __restrict__ deg, int N,
                                                   int* __restrict__ bsum) {
    int tid = threadIdx.x;
    int i = blockIdx.x * 256 + tid;
    int v = (i < N) ? deg[i] : 0;
    int lane = tid & 63, wid = tid >> 6;
    for (int off = 32; off; off >>= 1) v += __shfl_down(v, off);
    __shared__ int ws[4];
    if (lane == 0) ws[wid] = v;
    __syncthreads();
    if (tid == 0) bsum[blockIdx.x] = ws[0] + ws[1] + ws[2] + ws[3];
}

__global__ __launch_bounds__(256) void k_scan_top(int* __restrict__ bsum, int nb,
                                                  int* __restrict__ row_start, int N) {
    int tid = threadIdx.x;
    int lane = tid & 63, wid = tid >> 6;
    int v = (tid < nb) ? bsum[tid] : 0;
    int orig = v;
    for (int off = 1; off < 64; off <<= 1) {
        int t = __shfl_up(v, off);
        if (lane >= off) v += t;
    }
    __shared__ int ws[4];
    if (lane == 63) ws[wid] = v;
    __syncthreads();
    int woff = 0;
    for (int w = 0; w < 4; ++w)
        if (w < wid) woff += ws[w];
    if (tid < nb) bsum[tid] = woff + v - orig;
    if (tid == 0) row_start[N] = ws[0] + ws[1] + ws[2] + ws[3];
}

__global__ __launch_bounds__(256) void k_scan_final(const int* __restrict__ deg,
                                                    const int* __restrict__ bsum, int N,
                                                    int* __restrict__ row_start,
                                                    float* __restrict__ dis) {
    int tid = threadIdx.x;
    int i = blockIdx.x * 256 + tid;
    int v = (i < N) ? deg[i] : 0;
    int orig = v;
    int lane = tid & 63, wid = tid >> 6;
    for (int off = 1; off < 64; off <<= 1) {
        int t = __shfl_up(v, off);
        if (lane >= off) v += t;
    }
    __shared__ int ws[4];
    if (lane == 63) ws[wid] = v;
    __syncthreads();
    int woff = 0;
    for (int w = 0; w < 4; ++w)
        if (w < wid) woff += ws[w];
    if (i < N) {
        row_start[i] = bsum[blockIdx.x] + woff + v - orig;
        dis[i] = rsqrtf((float)(orig + 1));
    }
}

// ---------------- CSR fill (counting sort by dst) ----------------
__global__ void k_fill(const int* __restrict__ src, const int* __restrict__ dst, int E,
                       const int* __restrict__ row_start, int* __restrict__ cursor,
                       int* __restrict__ csr_src) {
    int e = blockIdx.x * blockDim.x + threadIdx.x;
    if (e < E) {
        int d = dst[e];
        int pos = atomicAdd(&cursor[d], 1);
        csr_src[row_start[d] + pos] = src[e];
    }
}

// ---------------- tiled GEMM: out[r][c] = dis[r] * sum_k X[r][k]*W[k][c]  (64 cols) ----------------
template <int K>
__global__ __launch_bounds__(256) void k_gemm_scale(const float* __restrict__ X,
                                                    const float* __restrict__ W,
                                                    const float* __restrict__ dis, int N,
                                                    float* __restrict__ out) {
    constexpr int KP = K + 4;
    constexpr int KC = K / 4;
    __shared__ float Xs[64 * KP];
    __shared__ float Ws[K * 64];
    int tid = threadIdx.x;
    int row0 = blockIdx.x * 64;

    const float4* Wg = (const float4*)W;
    float4* Ws4 = (float4*)Ws;
    for (int i = tid; i < K * 16; i += 256) Ws4[i] = Wg[i];
    const float4* Xg = (const float4*)X;
    for (int c = tid; c < 64 * KC; c += 256) {
        int r = c / KC, k4 = c % KC;
        int row = row0 + r;
        float4 vv = make_float4(0.f, 0.f, 0.f, 0.f);
        if (row < N) vv = Xg[(size_t)row * KC + k4];
        *(float4*)&Xs[r * KP + k4 * 4] = vv;
    }
    __syncthreads();

    int cg = tid & 15;
    int rg = tid >> 4;
    float acc[4][4] = {};
#pragma unroll 2
    for (int k = 0; k < K; k += 4) {
        float4 w0 = *(float4*)&Ws[(k + 0) * 64 + cg * 4];
        float4 w1 = *(float4*)&Ws[(k + 1) * 64 + cg * 4];
        float4 w2 = *(float4*)&Ws[(k + 2) * 64 + cg * 4];
        float4 w3 = *(float4*)&Ws[(k + 3) * 64 + cg * 4];
#pragma unroll
        for (int i = 0; i < 4; ++i) {
            float4 xv = *(float4*)&Xs[(rg * 4 + i) * KP + k];
            acc[i][0] += xv.x * w0.x + xv.y * w1.x + xv.z * w2.x + xv.w * w3.x;
            acc[i][1] += xv.x * w0.y + xv.y * w1.y + xv.z * w2.y + xv.w * w3.y;
            acc[i][2] += xv.x * w0.z + xv.y * w1.z + xv.z * w2.z + xv.w * w3.z;
            acc[i][3] += xv.x * w0.w + xv.y * w1.w + xv.z * w2.w + xv.w * w3.w;
        }
    }
#pragma unroll
    for (int i = 0; i < 4; ++i) {
        int row = row0 + rg * 4 + i;
        if (row < N) {
            float s = dis[row];
            *(float4*)&out[(size_t)row * 64 + cg * 4] =
                make_float4(acc[i][0] * s, acc[i][1] * s, acc[i][2] * s, acc[i][3] * s);
        }
    }
}

// ---------------- gather-aggregate v2: 4 edges in flight per wave (float4 rows) ----------------
// lane = g*16 + t ; subgroup g handles edge jb+g, lane covers channels 4t..4t+3
__global__ __launch_bounds__(256) void k_aggregate(const float* __restrict__ Hs,
                                                   const int* __restrict__ row_start,
                                                   const int* __restrict__ csr_src,
                                                   const float* __restrict__ dis,
                                                   const float* __restrict__ bias, int N,
                                                   float* __restrict__ out) {
    const float4* Hs4 = (const float4*)Hs;
    int wave = threadIdx.x >> 6, lane = threadIdx.x & 63;
    int node = blockIdx.x * 4 + wave;
    if (node >= N) return;
    int t = lane & 15, g = lane >> 4;
    float4 acc = make_float4(0.f, 0.f, 0.f, 0.f);
    if (g == 0) acc = Hs4[(size_t)node * 16 + t];  // self loop
    int e0 = row_start[node], e1 = row_start[node + 1];
    for (int eb = e0; eb < e1; eb += 64) {
        int cnt = min(64, e1 - eb);
        int sv = (eb + lane < e1) ? csr_src[eb + lane] : 0;
        for (int jb = 0; jb < cnt; jb += 4) {
            int idx = jb + g;
            int s = __shfl(sv, idx);
            float4 z = Hs4[(size_t)s * 16 + t];
            if (idx < cnt) {
                acc.x += z.x; acc.y += z.y; acc.z += z.z; acc.w += z.w;
            }
        }
    }
    // combine subgroup partials (xor over lane bits 4,5)
    acc.x += __shfl_xor(acc.x, 16); acc.y += __shfl_xor(acc.y, 16);
    acc.z += __shfl_xor(acc.z, 16); acc.w += __shfl_xor(acc.w, 16);
    acc.x += __shfl_xor(acc.x, 32); acc.y += __shfl_xor(acc.y, 32);
    acc.z += __shfl_xor(acc.z, 32); acc.w += __shfl_xor(acc.w, 32);
    float sc = dis[node];
    const float4* b4 = (const float4*)bias;
    float4 b = b4[t];
    float4 v;
    v.x = fmaxf(acc.x * sc + b.x, 0.f);
    v.y = fmaxf(acc.y * sc + b.y, 0.f);
    v.z = fmaxf(acc.z * sc + b.z, 0.f);
    v.w = fmaxf(acc.w * sc + b.w, 0.f);
    if (g == 0) ((float4*)out)[(size_t)node * 16 + t] = v;
}

// ---------------- aggregate v2 + fused head ----------------
__global__ __launch_bounds__(256) void k_aggregate_head(const float* __restrict__ Hs,
                                                        const int* __restrict__ row_start,
                                                        const int* __restrict__ csr_src,
                                                        const float* __restrict__ dis,
                                                        const float* __restrict__ bias,
                                                        const float* __restrict__ Wl,
                                                        const float* __restrict__ bl, int N,
                                                        float* __restrict__ out) {
    const float4* Hs4 = (const float4*)Hs;
    int wave = threadIdx.x >> 6, lane = threadIdx.x & 63;
    int node = blockIdx.x * 4 + wave;
    if (node >= N) return;
    int t = lane & 15, g = lane >> 4;
    float4 acc = make_float4(0.f, 0.f, 0.f, 0.f);
    if (g == 0) acc = Hs4[(size_t)node * 16 + t];
    int e0 = row_start[node], e1 = row_start[node + 1];
    for (int eb = e0; eb < e1; eb += 64) {
        int cnt = min(64, e1 - eb);
        int sv = (eb + lane < e1) ? csr_src[eb + lane] : 0;
        for (int jb = 0; jb < cnt; jb += 4) {
            int idx = jb + g;
            int s = __shfl(sv, idx);
            float4 z = Hs4[(size_t)s * 16 + t];
            if (idx < cnt) {
                acc.x += z.x; acc.y += z.y; acc.z += z.z; acc.w += z.w;
            }
        }
    }
    acc.x += __shfl_xor(acc.x, 16); acc.y += __shfl_xor(acc.y, 16);
    acc.z += __shfl_xor(acc.z, 16); acc.w += __shfl_xor(acc.w, 16);
    acc.x += __shfl_xor(acc.x, 32); acc.y += __shfl_xor(acc.y, 32);
    acc.z += __shfl_xor(acc.z, 32); acc.w += __shfl_xor(acc.w, 32);
    float sc = dis[node];
    const float4* b4 = (const float4*)bias;
    float4 b = b4[t];
    float4 v;
    v.x = fmaxf(acc.x * sc + b.x, 0.f);
    v.y = fmaxf(acc.y * sc + b.y, 0.f);
    v.z = fmaxf(acc.z * sc + b.z, 0.f);
    v.w = fmaxf(acc.w * sc + b.w, 0.f);
    // head: channels 4t..4t+3, Wl row-major [64][2]
    float a0 = v.x * Wl[(4 * t + 0) * 2] + v.y * Wl[(4 * t + 1) * 2] +
               v.z * Wl[(4 * t + 2) * 2] + v.w * Wl[(4 * t + 3) * 2];
    float a1 = v.x * Wl[(4 * t + 0) * 2 + 1] + v.y * Wl[(4 * t + 1) * 2 + 1] +
               v.z * Wl[(4 * t + 2) * 2 + 1] + v.w * Wl[(4 * t + 3) * 2 + 1];
    for (int off = 8; off; off >>= 1) {
        a0 += __shfl_down(a0, off);
        a1 += __shfl_down(a1, off);
    }
    if (lane == 0) {
        out[node * 2 + 0] = a0 + bl[0];
        out[node * 2 + 1] = a1 + bl[1];
    }
}

extern "C" void kernel_launch(void* const* d_in, const int* in_sizes, int n_in,
                              void* d_out, int out_size, void* d_ws, size_t ws_size,
                              hipStream_t stream) {
    const float* x  = (const float*)d_in[0];
    const int*   ei = (const int*)d_in[1];
    const float* W1 = (const float*)d_in[2];
    const float* b1 = (const float*)d_in[3];
    const float* W2 = (const float*)d_in[4];
    const float* b2 = (const float*)d_in[5];
    const float* Wl = (const float*)d_in[6];
    const float* bl = (const float*)d_in[7];

    const int N = in_sizes[0] / IN_DIM;   // 50000
    const int E = in_sizes[1] / 2;        // 800000
    const int* src = ei;
    const int* dst = ei + E;

    char* ws = (char*)d_ws;
    size_t off = 0;
    auto alloc = [&](size_t bytes) -> void* {
        void* p = ws + off;
        off = (off + bytes + 255) & ~(size_t)255;
        return p;
    };
    int*   deg       = (int*)alloc((size_t)N * 4);
    int*   row_start = (int*)alloc(((size_t)N + 1) * 4);
    int*   cursor    = (int*)alloc((size_t)N * 4);
    int*   csr_src   = (int*)alloc((size_t)E * 4);
    float* dis       = (float*)alloc((size_t)N * 4);
    int*   bsum      = (int*)alloc(1024 * 4);
    float* bufA      = (float*)alloc((size_t)N * HID * 4);
    float* bufB      = (float*)alloc((size_t)N * HID * 4);

    hipMemsetAsync(deg, 0, (size_t)N * 4, stream);
    hipMemsetAsync(cursor, 0, (size_t)N * 4, stream);

    int nb = (N + 255) / 256;
    k_count<<<(E + 255) / 256, 256, 0, stream>>>(dst, E, deg);
    k_scan_part<<<nb, 256, 0, stream>>>(deg, N, bsum);
    k_scan_top<<<1, 256, 0, stream>>>(bsum, nb, row_start, N);
    k_scan_final<<<nb, 256, 0, stream>>>(deg, bsum, N, row_start, dis);
    k_fill<<<(E + 255) / 256, 256, 0, stream>>>(src, dst, E, row_start, cursor, csr_src);

    int gblk = (N + 63) / 64;
    int nblk = (N + 3) / 4;
    k_gemm_scale<IN_DIM><<<gblk, 256, 0, stream>>>(x, W1, dis, N, bufA);
    k_aggregate<<<nblk, 256, 0, stream>>>(bufA, row_start, csr_src, dis, b1, N, bufB);
    k_gemm_scale<HID><<<gblk, 256, 0, stream>>>(bufB, W2, dis, N, bufA);
    k_aggregate_head<<<nblk, 256, 0, stream>>>(bufA, row_start, csr_src, dis, b2, Wl, bl, N,
                                               (float*)d_out);
}

// Round 6
// 174.659 us; speedup vs baseline: 3.7921x; 1.1243x over previous
//
#include <hip/hip_runtime.h>

#define IN_DIM 128
#define HID 64
#define STAGE_CAP 12288

// ---------------- degree count ----------------
__global__ void k_count(const int* __restrict__ dst, int E, int* __restrict__ deg) {
    int e = blockIdx.x * blockDim.x + threadIdx.x;
    if (e < E) atomicAdd(&deg[dst[e]], 1);
}

// ---------------- 3-phase scan ----------------
__global__ __launch_bounds__(256) void k_scan_part(const int* __restrict__ deg, int N,
                                                   int* __restrict__ bsum) {
    int tid = threadIdx.x;
    int i = blockIdx.x * 256 + tid;
    int v = (i < N) ? deg[i] : 0;
    int lane = tid & 63, wid = tid >> 6;
    for (int off = 32; off; off >>= 1) v += __shfl_down(v, off);
    __shared__ int ws[4];
    if (lane == 0) ws[wid] = v;
    __syncthreads();
    if (tid == 0) bsum[blockIdx.x] = ws[0] + ws[1] + ws[2] + ws[3];
}

__global__ __launch_bounds__(256) void k_scan_top(int* __restrict__ bsum, int nb,
                                                  int* __restrict__ row_start, int N) {
    int tid = threadIdx.x;
    int lane = tid & 63, wid = tid >> 6;
    int v = (tid < nb) ? bsum[tid] : 0;
    int orig = v;
    for (int off = 1; off < 64; off <<= 1) {
        int t = __shfl_up(v, off);
        if (lane >= off) v += t;
    }
    __shared__ int ws[4];
    if (lane == 63) ws[wid] = v;
    __syncthreads();
    int woff = 0;
    for (int w = 0; w < 4; ++w)
        if (w < wid) woff += ws[w];
    if (tid < nb) bsum[tid] = woff + v - orig;
    if (tid == 0) row_start[N] = ws[0] + ws[1] + ws[2] + ws[3];
}

__global__ __launch_bounds__(256) void k_scan_final(const int* __restrict__ deg,
                                                    const int* __restrict__ bsum, int N,
                                                    int* __restrict__ row_start,
                                                    float* __restrict__ dis) {
    int tid = threadIdx.x;
    int i = blockIdx.x * 256 + tid;
    int v = (i < N) ? deg[i] : 0;
    int orig = v;
    int lane = tid & 63, wid = tid >> 6;
    for (int off = 1; off < 64; off <<= 1) {
        int t = __shfl_up(v, off);
        if (lane >= off) v += t;
    }
    __shared__ int ws[4];
    if (lane == 63) ws[wid] = v;
    __syncthreads();
    int woff = 0;
    for (int w = 0; w < 4; ++w)
        if (w < wid) woff += ws[w];
    if (i < N) {
        row_start[i] = bsum[blockIdx.x] + woff + v - orig;
        dis[i] = rsqrtf((float)(orig + 1));
    }
}

// ---------------- CSR build, phase A: bucket-chunked scatter ----------------
// bucket = dst >> 8. Each block histograms its 8192 edges in LDS, claims one
// contiguous chunk per bucket (global atomic), writes packed (dstlo<<16|src)
// chunk-contiguously into ebuf. Requires N < 65536 (src fits 16 bits).
__global__ __launch_bounds__(512) void k_bin_scatter(const int* __restrict__ src,
                                                     const int* __restrict__ dst, int E,
                                                     const int* __restrict__ row_start,
                                                     int* __restrict__ gcur,
                                                     unsigned* __restrict__ ebuf) {
    __shared__ int hist[256];
    __shared__ int gbase[256];
    int tid = threadIdx.x;
    for (int i = tid; i < 256; i += 512) hist[i] = 0;
    __syncthreads();
    int base = blockIdx.x * 8192;
    int pk[16], bkt[16], rnk[16];
#pragma unroll
    for (int i = 0; i < 16; ++i) {
        int e = base + tid + i * 512;
        if (e < E) {
            int s = src[e];
            int d = dst[e];
            bkt[i] = d >> 8;
            pk[i] = ((d & 255) << 16) | s;
            rnk[i] = atomicAdd(&hist[bkt[i]], 1);
        } else {
            bkt[i] = -1;
        }
    }
    __syncthreads();
    for (int b = tid; b < 256; b += 512) {
        int c = hist[b];
        if (c > 0) gbase[b] = row_start[b << 8] + atomicAdd(&gcur[b], c);
    }
    __syncthreads();
#pragma unroll
    for (int i = 0; i < 16; ++i) {
        if (bkt[i] >= 0) ebuf[gbase[bkt[i]] + rnk[i]] = (unsigned)pk[i];
    }
}

// ---------------- CSR build, phase B: in-LDS counting sort per bucket ----------------
__global__ __launch_bounds__(512) void k_bin_sort(const unsigned* __restrict__ ebuf,
                                                  const int* __restrict__ row_start, int N,
                                                  int* __restrict__ csr_src) {
    __shared__ int lrs[257];
    __shared__ int lcur[256];
    __shared__ unsigned short stage[STAGE_CAP];
    int tid = threadIdx.x;
    int node0 = blockIdx.x << 8;
    int nnode = min(256, N - node0);
    for (int i = tid; i <= nnode; i += 512) lrs[i] = row_start[node0 + i];
    for (int i = tid; i < nnode; i += 512) lcur[i] = 0;
    __syncthreads();
    int bstart = lrs[0], bend = lrs[nnode];
    int cnt = bend - bstart;
    if (cnt <= STAGE_CAP) {
        for (int i = tid; i < cnt; i += 512) {
            unsigned u = ebuf[bstart + i];
            int dlo = (u >> 16) & 255;
            int pos = (lrs[dlo] - bstart) + atomicAdd(&lcur[dlo], 1);
            stage[pos] = (unsigned short)(u & 0xFFFF);
        }
        __syncthreads();
        for (int i = tid; i < cnt; i += 512) csr_src[bstart + i] = (int)stage[i];
    } else {  // fallback (never expected at E/N=16): direct scattered write
        for (int i = tid; i < cnt; i += 512) {
            unsigned u = ebuf[bstart + i];
            int dlo = (u >> 16) & 255;
            int pos = lrs[dlo] + atomicAdd(&lcur[dlo], 1);
            csr_src[pos] = (int)(u & 0xFFFF);
        }
    }
}

// ---------------- tiled GEMM: out[r][c] = dis[r] * sum_k X[r][k]*W[k][c]  (64 cols) ----------------
template <int K>
__global__ __launch_bounds__(256) void k_gemm_scale(const float* __restrict__ X,
                                                    const float* __restrict__ W,
                                                    const float* __restrict__ dis, int N,
                                                    float* __restrict__ out) {
    constexpr int KP = K + 4;
    constexpr int KC = K / 4;
    __shared__ float Xs[64 * KP];
    __shared__ float Ws[K * 64];
    int tid = threadIdx.x;
    int row0 = blockIdx.x * 64;

    const float4* Wg = (const float4*)W;
    float4* Ws4 = (float4*)Ws;
    for (int i = tid; i < K * 16; i += 256) Ws4[i] = Wg[i];
    const float4* Xg = (const float4*)X;
    for (int c = tid; c < 64 * KC; c += 256) {
        int r = c / KC, k4 = c % KC;
        int row = row0 + r;
        float4 vv = make_float4(0.f, 0.f, 0.f, 0.f);
        if (row < N) vv = Xg[(size_t)row * KC + k4];
        *(float4*)&Xs[r * KP + k4 * 4] = vv;
    }
    __syncthreads();

    int cg = tid & 15;
    int rg = tid >> 4;
    float acc[4][4] = {};
#pragma unroll 2
    for (int k = 0; k < K; k += 4) {
        float4 w0 = *(float4*)&Ws[(k + 0) * 64 + cg * 4];
        float4 w1 = *(float4*)&Ws[(k + 1) * 64 + cg * 4];
        float4 w2 = *(float4*)&Ws[(k + 2) * 64 + cg * 4];
        float4 w3 = *(float4*)&Ws[(k + 3) * 64 + cg * 4];
#pragma unroll
        for (int i = 0; i < 4; ++i) {
            float4 xv = *(float4*)&Xs[(rg * 4 + i) * KP + k];
            acc[i][0] += xv.x * w0.x + xv.y * w1.x + xv.z * w2.x + xv.w * w3.x;
            acc[i][1] += xv.x * w0.y + xv.y * w1.y + xv.z * w2.y + xv.w * w3.y;
            acc[i][2] += xv.x * w0.z + xv.y * w1.z + xv.z * w2.z + xv.w * w3.z;
            acc[i][3] += xv.x * w0.w + xv.y * w1.w + xv.z * w2.w + xv.w * w3.w;
        }
    }
#pragma unroll
    for (int i = 0; i < 4; ++i) {
        int row = row0 + rg * 4 + i;
        if (row < N) {
            float s = dis[row];
            *(float4*)&out[(size_t)row * 64 + cg * 4] =
                make_float4(acc[i][0] * s, acc[i][1] * s, acc[i][2] * s, acc[i][3] * s);
        }
    }
}

// ---------------- gather-aggregate v2: 4 edges in flight per wave (float4 rows) ----------------
__global__ __launch_bounds__(256) void k_aggregate(const float* __restrict__ Hs,
                                                   const int* __restrict__ row_start,
                                                   const int* __restrict__ csr_src,
                                                   const float* __restrict__ dis,
                                                   const float* __restrict__ bias, int N,
                                                   float* __restrict__ out) {
    const float4* Hs4 = (const float4*)Hs;
    int wave = threadIdx.x >> 6, lane = threadIdx.x & 63;
    int node = blockIdx.x * 4 + wave;
    if (node >= N) return;
    int t = lane & 15, g = lane >> 4;
    float4 acc = make_float4(0.f, 0.f, 0.f, 0.f);
    if (g == 0) acc = Hs4[(size_t)node * 16 + t];  // self loop
    int e0 = row_start[node], e1 = row_start[node + 1];
    for (int eb = e0; eb < e1; eb += 64) {
        int cnt = min(64, e1 - eb);
        int sv = (eb + lane < e1) ? csr_src[eb + lane] : 0;
        for (int jb = 0; jb < cnt; jb += 4) {
            int idx = jb + g;
            int s = __shfl(sv, idx);
            float4 z = Hs4[(size_t)s * 16 + t];
            if (idx < cnt) {
                acc.x += z.x; acc.y += z.y; acc.z += z.z; acc.w += z.w;
            }
        }
    }
    acc.x += __shfl_xor(acc.x, 16); acc.y += __shfl_xor(acc.y, 16);
    acc.z += __shfl_xor(acc.z, 16); acc.w += __shfl_xor(acc.w, 16);
    acc.x += __shfl_xor(acc.x, 32); acc.y += __shfl_xor(acc.y, 32);
    acc.z += __shfl_xor(acc.z, 32); acc.w += __shfl_xor(acc.w, 32);
    float sc = dis[node];
    const float4* b4 = (const float4*)bias;
    float4 b = b4[t];
    float4 v;
    v.x = fmaxf(acc.x * sc + b.x, 0.f);
    v.y = fmaxf(acc.y * sc + b.y, 0.f);
    v.z = fmaxf(acc.z * sc + b.z, 0.f);
    v.w = fmaxf(acc.w * sc + b.w, 0.f);
    if (g == 0) ((float4*)out)[(size_t)node * 16 + t] = v;
}

// ---------------- aggregate v2 + fused head ----------------
__global__ __launch_bounds__(256) void k_aggregate_head(const float* __restrict__ Hs,
                                                        const int* __restrict__ row_start,
                                                        const int* __restrict__ csr_src,
                                                        const float* __restrict__ dis,
                                                        const float* __restrict__ bias,
                                                        const float* __restrict__ Wl,
                                                        const float* __restrict__ bl, int N,
                                                        float* __restrict__ out) {
    const float4* Hs4 = (const float4*)Hs;
    int wave = threadIdx.x >> 6, lane = threadIdx.x & 63;
    int node = blockIdx.x * 4 + wave;
    if (node >= N) return;
    int t = lane & 15, g = lane >> 4;
    float4 acc = make_float4(0.f, 0.f, 0.f, 0.f);
    if (g == 0) acc = Hs4[(size_t)node * 16 + t];
    int e0 = row_start[node], e1 = row_start[node + 1];
    for (int eb = e0; eb < e1; eb += 64) {
        int cnt = min(64, e1 - eb);
        int sv = (eb + lane < e1) ? csr_src[eb + lane] : 0;
        for (int jb = 0; jb < cnt; jb += 4) {
            int idx = jb + g;
            int s = __shfl(sv, idx);
            float4 z = Hs4[(size_t)s * 16 + t];
            if (idx < cnt) {
                acc.x += z.x; acc.y += z.y; acc.z += z.z; acc.w += z.w;
            }
        }
    }
    acc.x += __shfl_xor(acc.x, 16); acc.y += __shfl_xor(acc.y, 16);
    acc.z += __shfl_xor(acc.z, 16); acc.w += __shfl_xor(acc.w, 16);
    acc.x += __shfl_xor(acc.x, 32); acc.y += __shfl_xor(acc.y, 32);
    acc.z += __shfl_xor(acc.z, 32); acc.w += __shfl_xor(acc.w, 32);
    float sc = dis[node];
    const float4* b4 = (const float4*)bias;
    float4 b = b4[t];
    float4 v;
    v.x = fmaxf(acc.x * sc + b.x, 0.f);
    v.y = fmaxf(acc.y * sc + b.y, 0.f);
    v.z = fmaxf(acc.z * sc + b.z, 0.f);
    v.w = fmaxf(acc.w * sc + b.w, 0.f);
    float a0 = v.x * Wl[(4 * t + 0) * 2] + v.y * Wl[(4 * t + 1) * 2] +
               v.z * Wl[(4 * t + 2) * 2] + v.w * Wl[(4 * t + 3) * 2];
    float a1 = v.x * Wl[(4 * t + 0) * 2 + 1] + v.y * Wl[(4 * t + 1) * 2 + 1] +
               v.z * Wl[(4 * t + 2) * 2 + 1] + v.w * Wl[(4 * t + 3) * 2 + 1];
    for (int off = 8; off; off >>= 1) {
        a0 += __shfl_down(a0, off);
        a1 += __shfl_down(a1, off);
    }
    if (lane == 0) {
        out[node * 2 + 0] = a0 + bl[0];
        out[node * 2 + 1] = a1 + bl[1];
    }
}

extern "C" void kernel_launch(void* const* d_in, const int* in_sizes, int n_in,
                              void* d_out, int out_size, void* d_ws, size_t ws_size,
                              hipStream_t stream) {
    const float* x  = (const float*)d_in[0];
    const int*   ei = (const int*)d_in[1];
    const float* W1 = (const float*)d_in[2];
    const float* b1 = (const float*)d_in[3];
    const float* W2 = (const float*)d_in[4];
    const float* b2 = (const float*)d_in[5];
    const float* Wl = (const float*)d_in[6];
    const float* bl = (const float*)d_in[7];

    const int N = in_sizes[0] / IN_DIM;   // 50000 (< 65536 required by packing)
    const int E = in_sizes[1] / 2;        // 800000
    const int* src = ei;
    const int* dst = ei + E;

    char* ws = (char*)d_ws;
    size_t off = 0;
    auto alloc = [&](size_t bytes) -> void* {
        void* p = ws + off;
        off = (off + bytes + 255) & ~(size_t)255;
        return p;
    };
    int*   deg       = (int*)alloc((size_t)N * 4);
    int*   row_start = (int*)alloc(((size_t)N + 1) * 4);
    int*   gcur      = (int*)alloc(256 * 4);
    int*   csr_src   = (int*)alloc((size_t)E * 4);
    float* dis       = (float*)alloc((size_t)N * 4);
    int*   bsum      = (int*)alloc(1024 * 4);
    float* bufA      = (float*)alloc((size_t)N * HID * 4);
    float* bufB      = (float*)alloc((size_t)N * HID * 4);
    unsigned* ebuf   = (unsigned*)bufA;  // alias: dead before first GEMM

    hipMemsetAsync(deg, 0, (size_t)N * 4, stream);
    hipMemsetAsync(gcur, 0, 256 * 4, stream);

    int nb = (N + 255) / 256;   // 196
    k_count<<<(E + 255) / 256, 256, 0, stream>>>(dst, E, deg);
    k_scan_part<<<nb, 256, 0, stream>>>(deg, N, bsum);
    k_scan_top<<<1, 256, 0, stream>>>(bsum, nb, row_start, N);
    k_scan_final<<<nb, 256, 0, stream>>>(deg, bsum, N, row_start, dis);
    k_bin_scatter<<<(E + 8191) / 8192, 512, 0, stream>>>(src, dst, E, row_start, gcur, ebuf);
    k_bin_sort<<<nb, 512, 0, stream>>>(ebuf, row_start, N, csr_src);

    int gblk = (N + 63) / 64;
    int nblk = (N + 3) / 4;
    k_gemm_scale<IN_DIM><<<gblk, 256, 0, stream>>>(x, W1, dis, N, bufA);
    k_aggregate<<<nblk, 256, 0, stream>>>(bufA, row_start, csr_src, dis, b1, N, bufB);
    k_gemm_scale<HID><<<gblk, 256, 0, stream>>>(bufB, W2, dis, N, bufA);
    k_aggregate_head<<<nblk, 256, 0, stream>>>(bufA, row_start, csr_src, dis, b2, Wl, bl, N,
                                               (float*)d_out);
}

// Round 7
// 168.574 us; speedup vs baseline: 3.9290x; 1.0361x over previous
//
#include <hip/hip_runtime.h>

#define IN_DIM 128
#define HID 64
#define STAGE_CAP 12288

// ---------------- init: zero deg + gcur in one dispatch ----------------
__global__ void k_init(int* __restrict__ deg, int* __restrict__ gcur, int N) {
    int i = blockIdx.x * blockDim.x + threadIdx.x;
    if (i < N) deg[i] = 0;
    if (i < 256) gcur[i] = 0;
}

// ---------------- degree count ----------------
__global__ void k_count(const int* __restrict__ dst, int E, int* __restrict__ deg) {
    int e = blockIdx.x * blockDim.x + threadIdx.x;
    if (e < E) atomicAdd(&deg[dst[e]], 1);
}

// ---------------- 3-phase scan ----------------
__global__ __launch_bounds__(256) void k_scan_part(const int* __restrict__ deg, int N,
                                                   int* __restrict__ bsum) {
    int tid = threadIdx.x;
    int i = blockIdx.x * 256 + tid;
    int v = (i < N) ? deg[i] : 0;
    int lane = tid & 63, wid = tid >> 6;
    for (int off = 32; off; off >>= 1) v += __shfl_down(v, off);
    __shared__ int ws[4];
    if (lane == 0) ws[wid] = v;
    __syncthreads();
    if (tid == 0) bsum[blockIdx.x] = ws[0] + ws[1] + ws[2] + ws[3];
}

__global__ __launch_bounds__(256) void k_scan_top(int* __restrict__ bsum, int nb,
                                                  int* __restrict__ row_start, int N) {
    int tid = threadIdx.x;
    int lane = tid & 63, wid = tid >> 6;
    int v = (tid < nb) ? bsum[tid] : 0;
    int orig = v;
    for (int off = 1; off < 64; off <<= 1) {
        int t = __shfl_up(v, off);
        if (lane >= off) v += t;
    }
    __shared__ int ws[4];
    if (lane == 63) ws[wid] = v;
    __syncthreads();
    int woff = 0;
    for (int w = 0; w < 4; ++w)
        if (w < wid) woff += ws[w];
    if (tid < nb) bsum[tid] = woff + v - orig;
    if (tid == 0) row_start[N] = ws[0] + ws[1] + ws[2] + ws[3];
}

__global__ __launch_bounds__(256) void k_scan_final(const int* __restrict__ deg,
                                                    const int* __restrict__ bsum, int N,
                                                    int* __restrict__ row_start,
                                                    float* __restrict__ dis) {
    int tid = threadIdx.x;
    int i = blockIdx.x * 256 + tid;
    int v = (i < N) ? deg[i] : 0;
    int orig = v;
    int lane = tid & 63, wid = tid >> 6;
    for (int off = 1; off < 64; off <<= 1) {
        int t = __shfl_up(v, off);
        if (lane >= off) v += t;
    }
    __shared__ int ws[4];
    if (lane == 63) ws[wid] = v;
    __syncthreads();
    int woff = 0;
    for (int w = 0; w < 4; ++w)
        if (w < wid) woff += ws[w];
    if (i < N) {
        row_start[i] = bsum[blockIdx.x] + woff + v - orig;
        dis[i] = rsqrtf((float)(orig + 1));
    }
}

// ---------------- CSR build, phase A: bucket-chunked scatter ----------------
// bucket = dst >> 8; 4096 edges/block. Requires N < 65536.
__global__ __launch_bounds__(512) void k_bin_scatter(const int* __restrict__ src,
                                                     const int* __restrict__ dst, int E,
                                                     const int* __restrict__ row_start,
                                                     int* __restrict__ gcur,
                                                     unsigned* __restrict__ ebuf) {
    __shared__ int hist[256];
    __shared__ int gbase[256];
    int tid = threadIdx.x;
    for (int i = tid; i < 256; i += 512) hist[i] = 0;
    __syncthreads();
    int base = blockIdx.x * 4096;
    int pk[8], bkt[8], rnk[8];
#pragma unroll
    for (int i = 0; i < 8; ++i) {
        int e = base + tid + i * 512;
        if (e < E) {
            int s = src[e];
            int d = dst[e];
            bkt[i] = d >> 8;
            pk[i] = ((d & 255) << 16) | s;
            rnk[i] = atomicAdd(&hist[bkt[i]], 1);
        } else {
            bkt[i] = -1;
        }
    }
    __syncthreads();
    for (int b = tid; b < 256; b += 512) {
        int c = hist[b];
        if (c > 0) gbase[b] = row_start[b << 8] + atomicAdd(&gcur[b], c);
    }
    __syncthreads();
#pragma unroll
    for (int i = 0; i < 8; ++i) {
        if (bkt[i] >= 0) ebuf[gbase[bkt[i]] + rnk[i]] = (unsigned)pk[i];
    }
}

// ---------------- CSR build, phase B: in-LDS counting sort per bucket ----------------
__global__ __launch_bounds__(512) void k_bin_sort(const unsigned* __restrict__ ebuf,
                                                  const int* __restrict__ row_start, int N,
                                                  int* __restrict__ csr_src) {
    __shared__ int lrs[257];
    __shared__ int lcur[256];
    __shared__ unsigned short stage[STAGE_CAP];
    int tid = threadIdx.x;
    int node0 = blockIdx.x << 8;
    int nnode = min(256, N - node0);
    for (int i = tid; i <= nnode; i += 512) lrs[i] = row_start[node0 + i];
    for (int i = tid; i < nnode; i += 512) lcur[i] = 0;
    __syncthreads();
    int bstart = lrs[0], bend = lrs[nnode];
    int cnt = bend - bstart;
    if (cnt <= STAGE_CAP) {
        for (int i = tid; i < cnt; i += 512) {
            unsigned u = ebuf[bstart + i];
            int dlo = (u >> 16) & 255;
            int pos = (lrs[dlo] - bstart) + atomicAdd(&lcur[dlo], 1);
            stage[pos] = (unsigned short)(u & 0xFFFF);
        }
        __syncthreads();
        for (int i = tid; i < cnt; i += 512) csr_src[bstart + i] = (int)stage[i];
    } else {
        for (int i = tid; i < cnt; i += 512) {
            unsigned u = ebuf[bstart + i];
            int dlo = (u >> 16) & 255;
            int pos = lrs[dlo] + atomicAdd(&lcur[dlo], 1);
            csr_src[pos] = (int)(u & 0xFFFF);
        }
    }
}

// ---------------- tiled GEMM: out[r][c] = dis[r] * sum_k X[r][k]*W[k][c]  (64 cols) ----------------
template <int K>
__global__ __launch_bounds__(256) void k_gemm_scale(const float* __restrict__ X,
                                                    const float* __restrict__ W,
                                                    const float* __restrict__ dis, int N,
                                                    float* __restrict__ out) {
    constexpr int KP = K + 4;
    constexpr int KC = K / 4;
    __shared__ float Xs[64 * KP];
    __shared__ float Ws[K * 64];
    int tid = threadIdx.x;
    int row0 = blockIdx.x * 64;

    const float4* Wg = (const float4*)W;
    float4* Ws4 = (float4*)Ws;
    for (int i = tid; i < K * 16; i += 256) Ws4[i] = Wg[i];
    const float4* Xg = (const float4*)X;
    for (int c = tid; c < 64 * KC; c += 256) {
        int r = c / KC, k4 = c % KC;
        int row = row0 + r;
        float4 vv = make_float4(0.f, 0.f, 0.f, 0.f);
        if (row < N) vv = Xg[(size_t)row * KC + k4];
        *(float4*)&Xs[r * KP + k4 * 4] = vv;
    }
    __syncthreads();

    int cg = tid & 15;
    int rg = tid >> 4;
    float acc[4][4] = {};
#pragma unroll 2
    for (int k = 0; k < K; k += 4) {
        float4 w0 = *(float4*)&Ws[(k + 0) * 64 + cg * 4];
        float4 w1 = *(float4*)&Ws[(k + 1) * 64 + cg * 4];
        float4 w2 = *(float4*)&Ws[(k + 2) * 64 + cg * 4];
        float4 w3 = *(float4*)&Ws[(k + 3) * 64 + cg * 4];
#pragma unroll
        for (int i = 0; i < 4; ++i) {
            float4 xv = *(float4*)&Xs[(rg * 4 + i) * KP + k];
            acc[i][0] += xv.x * w0.x + xv.y * w1.x + xv.z * w2.x + xv.w * w3.x;
            acc[i][1] += xv.x * w0.y + xv.y * w1.y + xv.z * w2.y + xv.w * w3.y;
            acc[i][2] += xv.x * w0.z + xv.y * w1.z + xv.z * w2.z + xv.w * w3.z;
            acc[i][3] += xv.x * w0.w + xv.y * w1.w + xv.z * w2.w + xv.w * w3.w;
        }
    }
#pragma unroll
    for (int i = 0; i < 4; ++i) {
        int row = row0 + rg * 4 + i;
        if (row < N) {
            float s = dis[row];
            *(float4*)&out[(size_t)row * 64 + cg * 4] =
                make_float4(acc[i][0] * s, acc[i][1] * s, acc[i][2] * s, acc[i][3] * s);
        }
    }
}

// ---------------- gather-aggregate v3: 8 edges in flight per wave ----------------
// lane = g*8 + t ; subgroup g handles edge jb+g; lane covers float4 t and t+8
__global__ __launch_bounds__(256) void k_aggregate(const float* __restrict__ Hs,
                                                   const int* __restrict__ row_start,
                                                   const int* __restrict__ csr_src,
                                                   const float* __restrict__ dis,
                                                   const float* __restrict__ bias, int N,
                                                   float* __restrict__ out) {
    const float4* Hs4 = (const float4*)Hs;
    int wave = threadIdx.x >> 6, lane = threadIdx.x & 63;
    int node = blockIdx.x * 4 + wave;
    if (node >= N) return;
    int t = lane & 7, g = lane >> 3;
    float4 a0 = make_float4(0.f, 0.f, 0.f, 0.f);
    float4 a1 = make_float4(0.f, 0.f, 0.f, 0.f);
    if (g == 0) {
        a0 = Hs4[(size_t)node * 16 + t];
        a1 = Hs4[(size_t)node * 16 + t + 8];
    }
    int e0 = row_start[node], e1 = row_start[node + 1];
    for (int eb = e0; eb < e1; eb += 64) {
        int cnt = min(64, e1 - eb);
        int sv = (eb + lane < e1) ? csr_src[eb + lane] : 0;
        for (int jb = 0; jb < cnt; jb += 8) {
            int idx = jb + g;
            int s = __shfl(sv, idx);
            float4 z0 = Hs4[(size_t)s * 16 + t];
            float4 z1 = Hs4[(size_t)s * 16 + t + 8];
            if (idx < cnt) {
                a0.x += z0.x; a0.y += z0.y; a0.z += z0.z; a0.w += z0.w;
                a1.x += z1.x; a1.y += z1.y; a1.z += z1.z; a1.w += z1.w;
            }
        }
    }
#pragma unroll
    for (int off = 8; off < 64; off <<= 1) {
        a0.x += __shfl_xor(a0.x, off); a0.y += __shfl_xor(a0.y, off);
        a0.z += __shfl_xor(a0.z, off); a0.w += __shfl_xor(a0.w, off);
        a1.x += __shfl_xor(a1.x, off); a1.y += __shfl_xor(a1.y, off);
        a1.z += __shfl_xor(a1.z, off); a1.w += __shfl_xor(a1.w, off);
    }
    float sc = dis[node];
    const float4* b4 = (const float4*)bias;
    float4 b0 = b4[t], b1 = b4[t + 8];
    float4 v0, v1;
    v0.x = fmaxf(a0.x * sc + b0.x, 0.f); v0.y = fmaxf(a0.y * sc + b0.y, 0.f);
    v0.z = fmaxf(a0.z * sc + b0.z, 0.f); v0.w = fmaxf(a0.w * sc + b0.w, 0.f);
    v1.x = fmaxf(a1.x * sc + b1.x, 0.f); v1.y = fmaxf(a1.y * sc + b1.y, 0.f);
    v1.z = fmaxf(a1.z * sc + b1.z, 0.f); v1.w = fmaxf(a1.w * sc + b1.w, 0.f);
    if (g == 0) ((float4*)out)[(size_t)node * 16 + t] = v0;
    if (g == 1) ((float4*)out)[(size_t)node * 16 + t + 8] = v1;
}

// ---------------- aggregate v3 + fused head ----------------
__global__ __launch_bounds__(256) void k_aggregate_head(const float* __restrict__ Hs,
                                                        const int* __restrict__ row_start,
                                                        const int* __restrict__ csr_src,
                                                        const float* __restrict__ dis,
                                                        const float* __restrict__ bias,
                                                        const float* __restrict__ Wl,
                                                        const float* __restrict__ bl, int N,
                                                        float* __restrict__ out) {
    const float4* Hs4 = (const float4*)Hs;
    int wave = threadIdx.x >> 6, lane = threadIdx.x & 63;
    int node = blockIdx.x * 4 + wave;
    if (node >= N) return;
    int t = lane & 7, g = lane >> 3;
    float4 a0 = make_float4(0.f, 0.f, 0.f, 0.f);
    float4 a1 = make_float4(0.f, 0.f, 0.f, 0.f);
    if (g == 0) {
        a0 = Hs4[(size_t)node * 16 + t];
        a1 = Hs4[(size_t)node * 16 + t + 8];
    }
    int e0 = row_start[node], e1 = row_start[node + 1];
    for (int eb = e0; eb < e1; eb += 64) {
        int cnt = min(64, e1 - eb);
        int sv = (eb + lane < e1) ? csr_src[eb + lane] : 0;
        for (int jb = 0; jb < cnt; jb += 8) {
            int idx = jb + g;
            int s = __shfl(sv, idx);
            float4 z0 = Hs4[(size_t)s * 16 + t];
            float4 z1 = Hs4[(size_t)s * 16 + t + 8];
            if (idx < cnt) {
                a0.x += z0.x; a0.y += z0.y; a0.z += z0.z; a0.w += z0.w;
                a1.x += z1.x; a1.y += z1.y; a1.z += z1.z; a1.w += z1.w;
            }
        }
    }
#pragma unroll
    for (int off = 8; off < 64; off <<= 1) {
        a0.x += __shfl_xor(a0.x, off); a0.y += __shfl_xor(a0.y, off);
        a0.z += __shfl_xor(a0.z, off); a0.w += __shfl_xor(a0.w, off);
        a1.x += __shfl_xor(a1.x, off); a1.y += __shfl_xor(a1.y, off);
        a1.z += __shfl_xor(a1.z, off); a1.w += __shfl_xor(a1.w, off);
    }
    float sc = dis[node];
    const float4* b4 = (const float4*)bias;
    float4 b0 = b4[t], b1 = b4[t + 8];
    float4 v0, v1;
    v0.x = fmaxf(a0.x * sc + b0.x, 0.f); v0.y = fmaxf(a0.y * sc + b0.y, 0.f);
    v0.z = fmaxf(a0.z * sc + b0.z, 0.f); v0.w = fmaxf(a0.w * sc + b0.w, 0.f);
    v1.x = fmaxf(a1.x * sc + b1.x, 0.f); v1.y = fmaxf(a1.y * sc + b1.y, 0.f);
    v1.z = fmaxf(a1.z * sc + b1.z, 0.f); v1.w = fmaxf(a1.w * sc + b1.w, 0.f);
    // head: v0 covers channels 4t..4t+3 ; v1 covers 32+4t..35+4t
    int c0 = 4 * t, c1 = 32 + 4 * t;
    float p0 = v0.x * Wl[(c0 + 0) * 2] + v0.y * Wl[(c0 + 1) * 2] +
               v0.z * Wl[(c0 + 2) * 2] + v0.w * Wl[(c0 + 3) * 2] +
               v1.x * Wl[(c1 + 0) * 2] + v1.y * Wl[(c1 + 1) * 2] +
               v1.z * Wl[(c1 + 2) * 2] + v1.w * Wl[(c1 + 3) * 2];
    float p1 = v0.x * Wl[(c0 + 0) * 2 + 1] + v0.y * Wl[(c0 + 1) * 2 + 1] +
               v0.z * Wl[(c0 + 2) * 2 + 1] + v0.w * Wl[(c0 + 3) * 2 + 1] +
               v1.x * Wl[(c1 + 0) * 2 + 1] + v1.y * Wl[(c1 + 1) * 2 + 1] +
               v1.z * Wl[(c1 + 2) * 2 + 1] + v1.w * Wl[(c1 + 3) * 2 + 1];
    // sum over t = low 3 lane bits (all groups hold identical totals)
    p0 += __shfl_xor(p0, 1); p1 += __shfl_xor(p1, 1);
    p0 += __shfl_xor(p0, 2); p1 += __shfl_xor(p1, 2);
    p0 += __shfl_xor(p0, 4); p1 += __shfl_xor(p1, 4);
    if (lane == 0) {
        out[node * 2 + 0] = p0 + bl[0];
        out[node * 2 + 1] = p1 + bl[1];
    }
}

extern "C" void kernel_launch(void* const* d_in, const int* in_sizes, int n_in,
                              void* d_out, int out_size, void* d_ws, size_t ws_size,
                              hipStream_t stream) {
    const float* x  = (const float*)d_in[0];
    const int*   ei = (const int*)d_in[1];
    const float* W1 = (const float*)d_in[2];
    const float* b1 = (const float*)d_in[3];
    const float* W2 = (const float*)d_in[4];
    const float* b2 = (const float*)d_in[5];
    const float* Wl = (const float*)d_in[6];
    const float* bl = (const float*)d_in[7];

    const int N = in_sizes[0] / IN_DIM;   // 50000 (< 65536 required by packing)
    const int E = in_sizes[1] / 2;        // 800000
    const int* src = ei;
    const int* dst = ei + E;

    char* ws = (char*)d_ws;
    size_t off = 0;
    auto alloc = [&](size_t bytes) -> void* {
        void* p = ws + off;
        off = (off + bytes + 255) & ~(size_t)255;
        return p;
    };
    int*   deg       = (int*)alloc((size_t)N * 4);
    int*   row_start = (int*)alloc(((size_t)N + 1) * 4);
    int*   gcur      = (int*)alloc(256 * 4);
    int*   csr_src   = (int*)alloc((size_t)E * 4);
    float* dis       = (float*)alloc((size_t)N * 4);
    int*   bsum      = (int*)alloc(1024 * 4);
    float* bufA      = (float*)alloc((size_t)N * HID * 4);
    float* bufB      = (float*)alloc((size_t)N * HID * 4);
    unsigned* ebuf   = (unsigned*)bufA;  // alias: dead before first GEMM

    int nb = (N + 255) / 256;   // 196
    k_init<<<nb, 256, 0, stream>>>(deg, gcur, N);
    k_count<<<(E + 255) / 256, 256, 0, stream>>>(dst, E, deg);
    k_scan_part<<<nb, 256, 0, stream>>>(deg, N, bsum);
    k_scan_top<<<1, 256, 0, stream>>>(bsum, nb, row_start, N);
    k_scan_final<<<nb, 256, 0, stream>>>(deg, bsum, N, row_start, dis);
    k_bin_scatter<<<(E + 4095) / 4096, 512, 0, stream>>>(src, dst, E, row_start, gcur, ebuf);
    k_bin_sort<<<nb, 512, 0, stream>>>(ebuf, row_start, N, csr_src);

    int gblk = (N + 63) / 64;
    int nblk = (N + 3) / 4;
    k_gemm_scale<IN_DIM><<<gblk, 256, 0, stream>>>(x, W1, dis, N, bufA);
    k_aggregate<<<nblk, 256, 0, stream>>>(bufA, row_start, csr_src, dis, b1, N, bufB);
    k_gemm_scale<HID><<<gblk, 256, 0, stream>>>(bufB, W2, dis, N, bufA);
    k_aggregate_head<<<nblk, 256, 0, stream>>>(bufA, row_start, csr_src, dis, b2, Wl, bl, N,
                                               (float*)d_out);
}

// Round 8
// 153.335 us; speedup vs baseline: 4.3195x; 1.0994x over previous
//
#include <hip/hip_runtime.h>

#define IN_DIM 128
#define HID 64
#define STAGE_CAP 12288

// ---------------- bucket histogram: bcnt[b] = #edges with dst>>8 == b ----------------
__global__ __launch_bounds__(256) void k_bin_count(const int* __restrict__ dst, int E,
                                                   int* __restrict__ bcnt) {
    __shared__ int h[256];
    int tid = threadIdx.x;
    h[tid] = 0;
    __syncthreads();
    int base = blockIdx.x * 4096;
    int end = min(base + 4096, E);
    for (int i = base + tid; i < end; i += 256) atomicAdd(&h[dst[i] >> 8], 1);
    __syncthreads();
    if (h[tid]) atomicAdd(&bcnt[tid], h[tid]);
}

// ---------------- bucket exclusive scan (256 entries) + gcur=0 + row_start[N]=E ----------------
__global__ __launch_bounds__(256) void k_bucket_scan(const int* __restrict__ bcnt,
                                                     int* __restrict__ bbase,
                                                     int* __restrict__ gcur,
                                                     int* __restrict__ row_start, int N, int E) {
    int tid = threadIdx.x, lane = tid & 63, wid = tid >> 6;
    int v = bcnt[tid], orig = v;
    for (int off = 1; off < 64; off <<= 1) {
        int t = __shfl_up(v, off);
        if (lane >= off) v += t;
    }
    __shared__ int ws[4];
    if (lane == 63) ws[wid] = v;
    __syncthreads();
    int woff = 0;
    for (int w = 0; w < wid; ++w) woff += ws[w];
    bbase[tid] = woff + v - orig;
    gcur[tid] = 0;
    if (tid == 0) row_start[N] = E;
}

// ---------------- CSR build, phase A: bucket-chunked scatter ----------------
// bucket = dst >> 8; 4096 edges/block. Requires N < 65536.
__global__ __launch_bounds__(512) void k_bin_scatter(const int* __restrict__ src,
                                                     const int* __restrict__ dst, int E,
                                                     const int* __restrict__ bbase,
                                                     int* __restrict__ gcur,
                                                     unsigned* __restrict__ ebuf) {
    __shared__ int hist[256];
    __shared__ int gbase[256];
    int tid = threadIdx.x;
    for (int i = tid; i < 256; i += 512) hist[i] = 0;
    __syncthreads();
    int base = blockIdx.x * 4096;
    int pk[8], bkt[8], rnk[8];
#pragma unroll
    for (int i = 0; i < 8; ++i) {
        int e = base + tid + i * 512;
        if (e < E) {
            int s = src[e];
            int d = dst[e];
            bkt[i] = d >> 8;
            pk[i] = ((d & 255) << 16) | s;
            rnk[i] = atomicAdd(&hist[bkt[i]], 1);
        } else {
            bkt[i] = -1;
        }
    }
    __syncthreads();
    for (int b = tid; b < 256; b += 512) {
        int c = hist[b];
        if (c > 0) gbase[b] = bbase[b] + atomicAdd(&gcur[b], c);
    }
    __syncthreads();
#pragma unroll
    for (int i = 0; i < 8; ++i) {
        if (bkt[i] >= 0) ebuf[gbase[bkt[i]] + rnk[i]] = (unsigned)pk[i];
    }
}

// ---------------- CSR build, phase B (fused): per-bucket degree count + scan
//                  -> row_start, dis, and in-LDS counting sort -> csr_src ----------------
__global__ __launch_bounds__(512) void k_bin_sort(const unsigned* __restrict__ ebuf,
                                                  const int* __restrict__ bbase, int N, int E,
                                                  int* __restrict__ row_start,
                                                  float* __restrict__ dis,
                                                  int* __restrict__ csr_src) {
    __shared__ int ldeg[256];
    __shared__ int loff[256];
    __shared__ int lcur[256];
    __shared__ int wsum[8];
    __shared__ unsigned short stage[STAGE_CAP];
    int tid = threadIdx.x;
    int node0 = blockIdx.x << 8;
    int nnode = min(256, N - node0);
    for (int i = tid; i < 256; i += 512) {
        ldeg[i] = 0;
        lcur[i] = 0;
    }
    __syncthreads();
    int bstart = bbase[blockIdx.x];
    int bend = bbase[blockIdx.x + 1];
    int cnt = bend - bstart;
    // pass 1: per-node degree within bucket
    for (int i = tid; i < cnt; i += 512) {
        unsigned u = ebuf[bstart + i];
        atomicAdd(&ldeg[(u >> 16) & 255], 1);
    }
    __syncthreads();
    // exclusive scan of ldeg (256 entries) using first 4 waves
    int lane = tid & 63, wid = tid >> 6;
    int v = 0, orig = 0;
    if (tid < 256) {
        orig = ldeg[tid];
        v = orig;
    }
    for (int off = 1; off < 64; off <<= 1) {
        int t = __shfl_up(v, off);
        if (lane >= off) v += t;
    }
    if (lane == 63) wsum[wid] = v;
    __syncthreads();
    if (tid < 256) {
        int woff = 0;
        for (int w = 0; w < wid && w < 4; ++w) woff += wsum[w];
        int excl = woff + v - orig;
        loff[tid] = excl;
        if (tid < nnode) {
            row_start[node0 + tid] = bstart + excl;
            dis[node0 + tid] = rsqrtf((float)(orig + 1));
        }
    }
    __syncthreads();
    // pass 2: place + coalesced write-out
    if (cnt <= STAGE_CAP) {
        for (int i = tid; i < cnt; i += 512) {
            unsigned u = ebuf[bstart + i];
            int dlo = (u >> 16) & 255;
            int pos = loff[dlo] + atomicAdd(&lcur[dlo], 1);
            stage[pos] = (unsigned short)(u & 0xFFFF);
        }
        __syncthreads();
        for (int i = tid; i < cnt; i += 512) csr_src[bstart + i] = (int)stage[i];
    } else {
        for (int i = tid; i < cnt; i += 512) {
            unsigned u = ebuf[bstart + i];
            int dlo = (u >> 16) & 255;
            int pos = bstart + loff[dlo] + atomicAdd(&lcur[dlo], 1);
            csr_src[pos] = (int)(u & 0xFFFF);
        }
    }
}

// ---------------- tiled GEMM: out[r][c] = dis[r] * sum_k X[r][k]*W[k][c]  (64 cols) ----------------
template <int K>
__global__ __launch_bounds__(256) void k_gemm_scale(const float* __restrict__ X,
                                                    const float* __restrict__ W,
                                                    const float* __restrict__ dis, int N,
                                                    float* __restrict__ out) {
    constexpr int KP = K + 4;
    constexpr int KC = K / 4;
    __shared__ float Xs[64 * KP];
    __shared__ float Ws[K * 64];
    int tid = threadIdx.x;
    int row0 = blockIdx.x * 64;

    const float4* Wg = (const float4*)W;
    float4* Ws4 = (float4*)Ws;
    for (int i = tid; i < K * 16; i += 256) Ws4[i] = Wg[i];
    const float4* Xg = (const float4*)X;
    for (int c = tid; c < 64 * KC; c += 256) {
        int r = c / KC, k4 = c % KC;
        int row = row0 + r;
        float4 vv = make_float4(0.f, 0.f, 0.f, 0.f);
        if (row < N) vv = Xg[(size_t)row * KC + k4];
        *(float4*)&Xs[r * KP + k4 * 4] = vv;
    }
    __syncthreads();

    int cg = tid & 15;
    int rg = tid >> 4;
    float acc[4][4] = {};
#pragma unroll 2
    for (int k = 0; k < K; k += 4) {
        float4 w0 = *(float4*)&Ws[(k + 0) * 64 + cg * 4];
        float4 w1 = *(float4*)&Ws[(k + 1) * 64 + cg * 4];
        float4 w2 = *(float4*)&Ws[(k + 2) * 64 + cg * 4];
        float4 w3 = *(float4*)&Ws[(k + 3) * 64 + cg * 4];
#pragma unroll
        for (int i = 0; i < 4; ++i) {
            float4 xv = *(float4*)&Xs[(rg * 4 + i) * KP + k];
            acc[i][0] += xv.x * w0.x + xv.y * w1.x + xv.z * w2.x + xv.w * w3.x;
            acc[i][1] += xv.x * w0.y + xv.y * w1.y + xv.z * w2.y + xv.w * w3.y;
            acc[i][2] += xv.x * w0.z + xv.y * w1.z + xv.z * w2.z + xv.w * w3.z;
            acc[i][3] += xv.x * w0.w + xv.y * w1.w + xv.z * w2.w + xv.w * w3.w;
        }
    }
#pragma unroll
    for (int i = 0; i < 4; ++i) {
        int row = row0 + rg * 4 + i;
        if (row < N) {
            float s = dis[row];
            *(float4*)&out[(size_t)row * 64 + cg * 4] =
                make_float4(acc[i][0] * s, acc[i][1] * s, acc[i][2] * s, acc[i][3] * s);
        }
    }
}

// ---------------- gather-aggregate v4: 16 edges in flight per wave ----------------
// lane = g*4 + t ; subgroup g (16 groups of 4 lanes) handles edge eb+g;
// lane covers float4s t, t+4, t+8, t+12 (4 independent 16B loads per iter)
__global__ __launch_bounds__(256) void k_aggregate(const float* __restrict__ Hs,
                                                   const int* __restrict__ row_start,
                                                   const int* __restrict__ csr_src,
                                                   const float* __restrict__ dis,
                                                   const float* __restrict__ bias, int N,
                                                   float* __restrict__ out) {
    const float4* Hs4 = (const float4*)Hs;
    int wave = threadIdx.x >> 6, lane = threadIdx.x & 63;
    int node = blockIdx.x * 4 + wave;
    if (node >= N) return;
    int t = lane & 3, g = lane >> 2;
    float4 a0 = make_float4(0.f, 0.f, 0.f, 0.f);
    float4 a1 = a0, a2 = a0, a3 = a0;
    if (g == 0) {
        a0 = Hs4[(size_t)node * 16 + t];
        a1 = Hs4[(size_t)node * 16 + t + 4];
        a2 = Hs4[(size_t)node * 16 + t + 8];
        a3 = Hs4[(size_t)node * 16 + t + 12];
    }
    int e0 = row_start[node], e1 = row_start[node + 1];
    for (int eb = e0; eb < e1; eb += 16) {
        int idx = eb + g;
        bool ok = idx < e1;
        int s = csr_src[ok ? idx : e0];
        size_t base = (size_t)s * 16;
        float4 z0 = Hs4[base + t];
        float4 z1 = Hs4[base + t + 4];
        float4 z2 = Hs4[base + t + 8];
        float4 z3 = Hs4[base + t + 12];
        if (ok) {
            a0.x += z0.x; a0.y += z0.y; a0.z += z0.z; a0.w += z0.w;
            a1.x += z1.x; a1.y += z1.y; a1.z += z1.z; a1.w += z1.w;
            a2.x += z2.x; a2.y += z2.y; a2.z += z2.z; a2.w += z2.w;
            a3.x += z3.x; a3.y += z3.y; a3.z += z3.z; a3.w += z3.w;
        }
    }
#pragma unroll
    for (int off = 4; off < 64; off <<= 1) {
        a0.x += __shfl_xor(a0.x, off); a0.y += __shfl_xor(a0.y, off);
        a0.z += __shfl_xor(a0.z, off); a0.w += __shfl_xor(a0.w, off);
        a1.x += __shfl_xor(a1.x, off); a1.y += __shfl_xor(a1.y, off);
        a1.z += __shfl_xor(a1.z, off); a1.w += __shfl_xor(a1.w, off);
        a2.x += __shfl_xor(a2.x, off); a2.y += __shfl_xor(a2.y, off);
        a2.z += __shfl_xor(a2.z, off); a2.w += __shfl_xor(a2.w, off);
        a3.x += __shfl_xor(a3.x, off); a3.y += __shfl_xor(a3.y, off);
        a3.z += __shfl_xor(a3.z, off); a3.w += __shfl_xor(a3.w, off);
    }
    float sc = dis[node];
    const float4* b4 = (const float4*)bias;
    float4 b0 = b4[t], b1 = b4[t + 4], b2 = b4[t + 8], b3 = b4[t + 12];
    float4 v0, v1, v2, v3;
    v0.x = fmaxf(a0.x * sc + b0.x, 0.f); v0.y = fmaxf(a0.y * sc + b0.y, 0.f);
    v0.z = fmaxf(a0.z * sc + b0.z, 0.f); v0.w = fmaxf(a0.w * sc + b0.w, 0.f);
    v1.x = fmaxf(a1.x * sc + b1.x, 0.f); v1.y = fmaxf(a1.y * sc + b1.y, 0.f);
    v1.z = fmaxf(a1.z * sc + b1.z, 0.f); v1.w = fmaxf(a1.w * sc + b1.w, 0.f);
    v2.x = fmaxf(a2.x * sc + b2.x, 0.f); v2.y = fmaxf(a2.y * sc + b2.y, 0.f);
    v2.z = fmaxf(a2.z * sc + b2.z, 0.f); v2.w = fmaxf(a2.w * sc + b2.w, 0.f);
    v3.x = fmaxf(a3.x * sc + b3.x, 0.f); v3.y = fmaxf(a3.y * sc + b3.y, 0.f);
    v3.z = fmaxf(a3.z * sc + b3.z, 0.f); v3.w = fmaxf(a3.w * sc + b3.w, 0.f);
    if (g == 0) {
        float4* o4 = (float4*)out;
        o4[(size_t)node * 16 + t] = v0;
        o4[(size_t)node * 16 + t + 4] = v1;
        o4[(size_t)node * 16 + t + 8] = v2;
        o4[(size_t)node * 16 + t + 12] = v3;
    }
}

// ---------------- aggregate v4 + fused head ----------------
__global__ __launch_bounds__(256) void k_aggregate_head(const float* __restrict__ Hs,
                                                        const int* __restrict__ row_start,
                                                        const int* __restrict__ csr_src,
                                                        const float* __restrict__ dis,
                                                        const float* __restrict__ bias,
                                                        const float* __restrict__ Wl,
                                                        const float* __restrict__ bl, int N,
                                                        float* __restrict__ out) {
    const float4* Hs4 = (const float4*)Hs;
    int wave = threadIdx.x >> 6, lane = threadIdx.x & 63;
    int node = blockIdx.x * 4 + wave;
    if (node >= N) return;
    int t = lane & 3, g = lane >> 2;
    float4 a0 = make_float4(0.f, 0.f, 0.f, 0.f);
    float4 a1 = a0, a2 = a0, a3 = a0;
    if (g == 0) {
        a0 = Hs4[(size_t)node * 16 + t];
        a1 = Hs4[(size_t)node * 16 + t + 4];
        a2 = Hs4[(size_t)node * 16 + t + 8];
        a3 = Hs4[(size_t)node * 16 + t + 12];
    }
    int e0 = row_start[node], e1 = row_start[node + 1];
    for (int eb = e0; eb < e1; eb += 16) {
        int idx = eb + g;
        bool ok = idx < e1;
        int s = csr_src[ok ? idx : e0];
        size_t base = (size_t)s * 16;
        float4 z0 = Hs4[base + t];
        float4 z1 = Hs4[base + t + 4];
        float4 z2 = Hs4[base + t + 8];
        float4 z3 = Hs4[base + t + 12];
        if (ok) {
            a0.x += z0.x; a0.y += z0.y; a0.z += z0.z; a0.w += z0.w;
            a1.x += z1.x; a1.y += z1.y; a1.z += z1.z; a1.w += z1.w;
            a2.x += z2.x; a2.y += z2.y; a2.z += z2.z; a2.w += z2.w;
            a3.x += z3.x; a3.y += z3.y; a3.z += z3.z; a3.w += z3.w;
        }
    }
#pragma unroll
    for (int off = 4; off < 64; off <<= 1) {
        a0.x += __shfl_xor(a0.x, off); a0.y += __shfl_xor(a0.y, off);
        a0.z += __shfl_xor(a0.z, off); a0.w += __shfl_xor(a0.w, off);
        a1.x += __shfl_xor(a1.x, off); a1.y += __shfl_xor(a1.y, off);
        a1.z += __shfl_xor(a1.z, off); a1.w += __shfl_xor(a1.w, off);
        a2.x += __shfl_xor(a2.x, off); a2.y += __shfl_xor(a2.y, off);
        a2.z += __shfl_xor(a2.z, off); a2.w += __shfl_xor(a2.w, off);
        a3.x += __shfl_xor(a3.x, off); a3.y += __shfl_xor(a3.y, off);
        a3.z += __shfl_xor(a3.z, off); a3.w += __shfl_xor(a3.w, off);
    }
    float sc = dis[node];
    const float4* b4 = (const float4*)bias;
    float4 b0 = b4[t], b1 = b4[t + 4], b2 = b4[t + 8], b3 = b4[t + 12];
    float4 v0, v1, v2, v3;
    v0.x = fmaxf(a0.x * sc + b0.x, 0.f); v0.y = fmaxf(a0.y * sc + b0.y, 0.f);
    v0.z = fmaxf(a0.z * sc + b0.z, 0.f); v0.w = fmaxf(a0.w * sc + b0.w, 0.f);
    v1.x = fmaxf(a1.x * sc + b1.x, 0.f); v1.y = fmaxf(a1.y * sc + b1.y, 0.f);
    v1.z = fmaxf(a1.z * sc + b1.z, 0.f); v1.w = fmaxf(a1.w * sc + b1.w, 0.f);
    v2.x = fmaxf(a2.x * sc + b2.x, 0.f); v2.y = fmaxf(a2.y * sc + b2.y, 0.f);
    v2.z = fmaxf(a2.z * sc + b2.z, 0.f); v2.w = fmaxf(a2.w * sc + b2.w, 0.f);
    v3.x = fmaxf(a3.x * sc + b3.x, 0.f); v3.y = fmaxf(a3.y * sc + b3.y, 0.f);
    v3.z = fmaxf(a3.z * sc + b3.z, 0.f); v3.w = fmaxf(a3.w * sc + b3.w, 0.f);
    // head: float4 j covers channels 4*(t+4j) .. 4*(t+4j)+3
    int c0 = 4 * t, c1 = 4 * (t + 4), c2 = 4 * (t + 8), c3 = 4 * (t + 12);
    float p0 = v0.x * Wl[(c0 + 0) * 2] + v0.y * Wl[(c0 + 1) * 2] +
               v0.z * Wl[(c0 + 2) * 2] + v0.w * Wl[(c0 + 3) * 2] +
               v1.x * Wl[(c1 + 0) * 2] + v1.y * Wl[(c1 + 1) * 2] +
               v1.z * Wl[(c1 + 2) * 2] + v1.w * Wl[(c1 + 3) * 2] +
               v2.x * Wl[(c2 + 0) * 2] + v2.y * Wl[(c2 + 1) * 2] +
               v2.z * Wl[(c2 + 2) * 2] + v2.w * Wl[(c2 + 3) * 2] +
               v3.x * Wl[(c3 + 0) * 2] + v3.y * Wl[(c3 + 1) * 2] +
               v3.z * Wl[(c3 + 2) * 2] + v3.w * Wl[(c3 + 3) * 2];
    float p1 = v0.x * Wl[(c0 + 0) * 2 + 1] + v0.y * Wl[(c0 + 1) * 2 + 1] +
               v0.z * Wl[(c0 + 2) * 2 + 1] + v0.w * Wl[(c0 + 3) * 2 + 1] +
               v1.x * Wl[(c1 + 0) * 2 + 1] + v1.y * Wl[(c1 + 1) * 2 + 1] +
               v1.z * Wl[(c1 + 2) * 2 + 1] + v1.w * Wl[(c1 + 3) * 2 + 1] +
               v2.x * Wl[(c2 + 0) * 2 + 1] + v2.y * Wl[(c2 + 1) * 2 + 1] +
               v2.z * Wl[(c2 + 2) * 2 + 1] + v2.w * Wl[(c2 + 3) * 2 + 1] +
               v3.x * Wl[(c3 + 0) * 2 + 1] + v3.y * Wl[(c3 + 1) * 2 + 1] +
               v3.z * Wl[(c3 + 2) * 2 + 1] + v3.w * Wl[(c3 + 3) * 2 + 1];
    // reduce over t (lane bits 0-1); all g-copies identical after the xor reduce above
    p0 += __shfl_xor(p0, 1); p1 += __shfl_xor(p1, 1);
    p0 += __shfl_xor(p0, 2); p1 += __shfl_xor(p1, 2);
    if (lane == 0) {
        out[node * 2 + 0] = p0 + bl[0];
        out[node * 2 + 1] = p1 + bl[1];
    }
}

extern "C" void kernel_launch(void* const* d_in, const int* in_sizes, int n_in,
                              void* d_out, int out_size, void* d_ws, size_t ws_size,
                              hipStream_t stream) {
    const float* x  = (const float*)d_in[0];
    const int*   ei = (const int*)d_in[1];
    const float* W1 = (const float*)d_in[2];
    const float* b1 = (const float*)d_in[3];
    const float* W2 = (const float*)d_in[4];
    const float* b2 = (const float*)d_in[5];
    const float* Wl = (const float*)d_in[6];
    const float* bl = (const float*)d_in[7];

    const int N = in_sizes[0] / IN_DIM;   // 50000 (< 65536 required by packing)
    const int E = in_sizes[1] / 2;        // 800000
    const int* src = ei;
    const int* dst = ei + E;

    char* ws = (char*)d_ws;
    size_t off = 0;
    auto alloc = [&](size_t bytes) -> void* {
        void* p = ws + off;
        off = (off + bytes + 255) & ~(size_t)255;
        return p;
    };
    int*   bcnt      = (int*)alloc(256 * 4);
    int*   bbase     = (int*)alloc(257 * 4);
    int*   gcur      = (int*)alloc(256 * 4);
    int*   row_start = (int*)alloc(((size_t)N + 1) * 4);
    float* dis       = (float*)alloc((size_t)N * 4);
    int*   csr_src   = (int*)alloc((size_t)E * 4);
    float* bufA      = (float*)alloc((size_t)N * HID * 4);
    float* bufB      = (float*)alloc((size_t)N * HID * 4);
    unsigned* ebuf   = (unsigned*)bufA;  // alias: dead before first GEMM

    hipMemsetAsync(bcnt, 0, 256 * 4, stream);

    int eblk = (E + 4095) / 4096;  // 196
    int nb = (N + 255) / 256;      // 196
    k_bin_count<<<eblk, 256, 0, stream>>>(dst, E, bcnt);
    k_bucket_scan<<<1, 256, 0, stream>>>(bcnt, bbase, gcur, row_start, N, E);
    k_bin_scatter<<<eblk, 512, 0, stream>>>(src, dst, E, bbase, gcur, ebuf);
    k_bin_sort<<<nb, 512, 0, stream>>>(ebuf, bbase, N, E, row_start, dis, csr_src);

    int gblk = (N + 63) / 64;
    int nblk = (N + 3) / 4;
    k_gemm_scale<IN_DIM><<<gblk, 256, 0, stream>>>(x, W1, dis, N, bufA);
    k_aggregate<<<nblk, 256, 0, stream>>>(bufA, row_start, csr_src, dis, b1, N, bufB);
    k_gemm_scale<HID><<<gblk, 256, 0, stream>>>(bufB, W2, dis, N, bufA);
    k_aggregate_head<<<nblk, 256, 0, stream>>>(bufA, row_start, csr_src, dis, b2, Wl, bl, N,
                                               (float*)d_out);
}

// Round 9
// 135.131 us; speedup vs baseline: 4.9014x; 1.1347x over previous
//
#include <hip/hip_runtime.h>

#define IN_DIM 128
#define HID 64
#define STAGE_CAP 12288

// ---------------- bucket histogram: bcnt[b] = #edges with dst>>8 == b ----------------
__global__ __launch_bounds__(256) void k_bin_count(const int* __restrict__ dst, int E,
                                                   int* __restrict__ bcnt) {
    __shared__ int h[256];
    int tid = threadIdx.x;
    h[tid] = 0;
    __syncthreads();
    int base = blockIdx.x * 4096;
    int end = min(base + 4096, E);
    for (int i = base + tid; i < end; i += 256) atomicAdd(&h[dst[i] >> 8], 1);
    __syncthreads();
    if (h[tid]) atomicAdd(&bcnt[tid], h[tid]);
}

// ---------------- bucket exclusive scan (256 entries) + gcur=0 + row_start[N]=E ----------------
__global__ __launch_bounds__(256) void k_bucket_scan(const int* __restrict__ bcnt,
                                                     int* __restrict__ bbase,
                                                     int* __restrict__ gcur,
                                                     int* __restrict__ row_start, int N, int E) {
    int tid = threadIdx.x, lane = tid & 63, wid = tid >> 6;
    int v = bcnt[tid], orig = v;
    for (int off = 1; off < 64; off <<= 1) {
        int t = __shfl_up(v, off);
        if (lane >= off) v += t;
    }
    __shared__ int ws[4];
    if (lane == 63) ws[wid] = v;
    __syncthreads();
    int woff = 0;
    for (int w = 0; w < wid; ++w) woff += ws[w];
    bbase[tid] = woff + v - orig;
    gcur[tid] = 0;
    if (tid == 0) row_start[N] = E;
    if (tid == 0) bbase[256] = E;
}

// ---------------- CSR build, phase A: bucket-chunked scatter ----------------
// bucket = dst >> 8; 4096 edges/block. Requires N < 65536.
__global__ __launch_bounds__(512) void k_bin_scatter(const int* __restrict__ src,
                                                     const int* __restrict__ dst, int E,
                                                     const int* __restrict__ bbase,
                                                     int* __restrict__ gcur,
                                                     unsigned* __restrict__ ebuf) {
    __shared__ int hist[256];
    __shared__ int gbase[256];
    int tid = threadIdx.x;
    for (int i = tid; i < 256; i += 512) hist[i] = 0;
    __syncthreads();
    int base = blockIdx.x * 4096;
    int pk[8], bkt[8], rnk[8];
#pragma unroll
    for (int i = 0; i < 8; ++i) {
        int e = base + tid + i * 512;
        if (e < E) {
            int s = src[e];
            int d = dst[e];
            bkt[i] = d >> 8;
            pk[i] = ((d & 255) << 16) | s;
            rnk[i] = atomicAdd(&hist[bkt[i]], 1);
        } else {
            bkt[i] = -1;
        }
    }
    __syncthreads();
    for (int b = tid; b < 256; b += 512) {
        int c = hist[b];
        if (c > 0) gbase[b] = bbase[b] + atomicAdd(&gcur[b], c);
    }
    __syncthreads();
#pragma unroll
    for (int i = 0; i < 8; ++i) {
        if (bkt[i] >= 0) ebuf[gbase[bkt[i]] + rnk[i]] = (unsigned)pk[i];
    }
}

// ---------------- CSR build, phase B (fused): per-bucket degree count + scan
//                  -> row_start, dis, and in-LDS counting sort -> csr_src ----------------
__global__ __launch_bounds__(512) void k_bin_sort(const unsigned* __restrict__ ebuf,
                                                  const int* __restrict__ bbase, int N, int E,
                                                  int* __restrict__ row_start,
                                                  float* __restrict__ dis,
                                                  int* __restrict__ csr_src) {
    __shared__ int ldeg[256];
    __shared__ int loff[256];
    __shared__ int lcur[256];
    __shared__ int wsum[8];
    __shared__ unsigned short stage[STAGE_CAP];
    int tid = threadIdx.x;
    int node0 = blockIdx.x << 8;
    int nnode = min(256, N - node0);
    for (int i = tid; i < 256; i += 512) {
        ldeg[i] = 0;
        lcur[i] = 0;
    }
    __syncthreads();
    int bstart = bbase[blockIdx.x];
    int bend = bbase[blockIdx.x + 1];
    int cnt = bend - bstart;
    // pass 1: per-node degree within bucket
    for (int i = tid; i < cnt; i += 512) {
        unsigned u = ebuf[bstart + i];
        atomicAdd(&ldeg[(u >> 16) & 255], 1);
    }
    __syncthreads();
    // exclusive scan of ldeg (256 entries) using first 4 waves
    int lane = tid & 63, wid = tid >> 6;
    int v = 0, orig = 0;
    if (tid < 256) {
        orig = ldeg[tid];
        v = orig;
    }
    for (int off = 1; off < 64; off <<= 1) {
        int t = __shfl_up(v, off);
        if (lane >= off) v += t;
    }
    if (lane == 63) wsum[wid] = v;
    __syncthreads();
    if (tid < 256) {
        int woff = 0;
        for (int w = 0; w < wid && w < 4; ++w) woff += wsum[w];
        int excl = woff + v - orig;
        loff[tid] = excl;
        if (tid < nnode) {
            row_start[node0 + tid] = bstart + excl;
            dis[node0 + tid] = rsqrtf((float)(orig + 1));
        }
    }
    __syncthreads();
    // pass 2: place + coalesced write-out
    if (cnt <= STAGE_CAP) {
        for (int i = tid; i < cnt; i += 512) {
            unsigned u = ebuf[bstart + i];
            int dlo = (u >> 16) & 255;
            int pos = loff[dlo] + atomicAdd(&lcur[dlo], 1);
            stage[pos] = (unsigned short)(u & 0xFFFF);
        }
        __syncthreads();
        for (int i = tid; i < cnt; i += 512) csr_src[bstart + i] = (int)stage[i];
    } else {
        for (int i = tid; i < cnt; i += 512) {
            unsigned u = ebuf[bstart + i];
            int dlo = (u >> 16) & 255;
            int pos = bstart + loff[dlo] + atomicAdd(&lcur[dlo], 1);
            csr_src[pos] = (int)(u & 0xFFFF);
        }
    }
}

// ---------------- tiled GEMM: out[r][c] = dis[r] * sum_k X[r][k]*W[k][c]  (64 cols) ----------------
template <int K>
__global__ __launch_bounds__(256) void k_gemm_scale(const float* __restrict__ X,
                                                    const float* __restrict__ W,
                                                    const float* __restrict__ dis, int N,
                                                    float* __restrict__ out) {
    constexpr int KP = K + 4;
    constexpr int KC = K / 4;
    __shared__ float Xs[64 * KP];
    __shared__ float Ws[K * 64];
    int tid = threadIdx.x;
    int row0 = blockIdx.x * 64;

    const float4* Wg = (const float4*)W;
    float4* Ws4 = (float4*)Ws;
    for (int i = tid; i < K * 16; i += 256) Ws4[i] = Wg[i];
    const float4* Xg = (const float4*)X;
    for (int c = tid; c < 64 * KC; c += 256) {
        int r = c / KC, k4 = c % KC;
        int row = row0 + r;
        float4 vv = make_float4(0.f, 0.f, 0.f, 0.f);
        if (row < N) vv = Xg[(size_t)row * KC + k4];
        *(float4*)&Xs[r * KP + k4 * 4] = vv;
    }
    __syncthreads();

    int cg = tid & 15;
    int rg = tid >> 4;
    float acc[4][4] = {};
#pragma unroll 2
    for (int k = 0; k < K; k += 4) {
        float4 w0 = *(float4*)&Ws[(k + 0) * 64 + cg * 4];
        float4 w1 = *(float4*)&Ws[(k + 1) * 64 + cg * 4];
        float4 w2 = *(float4*)&Ws[(k + 2) * 64 + cg * 4];
        float4 w3 = *(float4*)&Ws[(k + 3) * 64 + cg * 4];
#pragma unroll
        for (int i = 0; i < 4; ++i) {
            float4 xv = *(float4*)&Xs[(rg * 4 + i) * KP + k];
            acc[i][0] += xv.x * w0.x + xv.y * w1.x + xv.z * w2.x + xv.w * w3.x;
            acc[i][1] += xv.x * w0.y + xv.y * w1.y + xv.z * w2.y + xv.w * w3.y;
            acc[i][2] += xv.x * w0.z + xv.y * w1.z + xv.z * w2.z + xv.w * w3.z;
            acc[i][3] += xv.x * w0.w + xv.y * w1.w + xv.z * w2.w + xv.w * w3.w;
        }
    }
#pragma unroll
    for (int i = 0; i < 4; ++i) {
        int row = row0 + rg * 4 + i;
        if (row < N) {
            float s = dis[row];
            *(float4*)&out[(size_t)row * 64 + cg * 4] =
                make_float4(acc[i][0] * s, acc[i][1] * s, acc[i][2] * s, acc[i][3] * s);
        }
    }
}

// ---------------- gather-aggregate v5: 8-lane subgroups, unroll x2, hoisted loads ----------------
// lane = g*8 + t ; subgroup g handles edges jb+g and jb+8+g; lane covers float4 t and t+8.
// All 4 gather loads issue before any add (single waitcnt region, 4 in flight);
// adds predicated per subgroup; OOB indices clamped to a hot row (cache hit).
__global__ __launch_bounds__(256) void k_aggregate(const float* __restrict__ Hs,
                                                   const int* __restrict__ row_start,
                                                   const int* __restrict__ csr_src,
                                                   const float* __restrict__ dis,
                                                   const float* __restrict__ bias, int N,
                                                   float* __restrict__ out) {
    const float4* Hs4 = (const float4*)Hs;
    int wave = threadIdx.x >> 6, lane = threadIdx.x & 63;
    int node = blockIdx.x * 4 + wave;
    if (node >= N) return;
    int t = lane & 7, g = lane >> 3;
    float4 a0 = make_float4(0.f, 0.f, 0.f, 0.f);
    float4 a1 = a0;
    if (g == 0) {
        a0 = Hs4[(size_t)node * 16 + t];
        a1 = Hs4[(size_t)node * 16 + t + 8];
    }
    int e0 = row_start[node], e1 = row_start[node + 1];
    for (int eb = e0; eb < e1; eb += 64) {
        int cnt = min(64, e1 - eb);
        int sv = (eb + lane < e1) ? csr_src[eb + lane] : 0;
        for (int jb = 0; jb < cnt; jb += 16) {
            int i0 = jb + g, i1 = jb + 8 + g;
            int s0 = __shfl(sv, i0 < cnt ? i0 : 0);
            int s1 = __shfl(sv, i1 < cnt ? i1 : 0);
            size_t b0 = (size_t)s0 * 16, b1 = (size_t)s1 * 16;
            float4 z00 = Hs4[b0 + t];
            float4 z01 = Hs4[b0 + t + 8];
            float4 z10 = Hs4[b1 + t];
            float4 z11 = Hs4[b1 + t + 8];
            if (i0 < cnt) {
                a0.x += z00.x; a0.y += z00.y; a0.z += z00.z; a0.w += z00.w;
                a1.x += z01.x; a1.y += z01.y; a1.z += z01.z; a1.w += z01.w;
            }
            if (i1 < cnt) {
                a0.x += z10.x; a0.y += z10.y; a0.z += z10.z; a0.w += z10.w;
                a1.x += z11.x; a1.y += z11.y; a1.z += z11.z; a1.w += z11.w;
            }
        }
    }
#pragma unroll
    for (int off = 8; off < 64; off <<= 1) {
        a0.x += __shfl_xor(a0.x, off); a0.y += __shfl_xor(a0.y, off);
        a0.z += __shfl_xor(a0.z, off); a0.w += __shfl_xor(a0.w, off);
        a1.x += __shfl_xor(a1.x, off); a1.y += __shfl_xor(a1.y, off);
        a1.z += __shfl_xor(a1.z, off); a1.w += __shfl_xor(a1.w, off);
    }
    float sc = dis[node];
    const float4* b4 = (const float4*)bias;
    float4 b0 = b4[t], b1 = b4[t + 8];
    float4 v0, v1;
    v0.x = fmaxf(a0.x * sc + b0.x, 0.f); v0.y = fmaxf(a0.y * sc + b0.y, 0.f);
    v0.z = fmaxf(a0.z * sc + b0.z, 0.f); v0.w = fmaxf(a0.w * sc + b0.w, 0.f);
    v1.x = fmaxf(a1.x * sc + b1.x, 0.f); v1.y = fmaxf(a1.y * sc + b1.y, 0.f);
    v1.z = fmaxf(a1.z * sc + b1.z, 0.f); v1.w = fmaxf(a1.w * sc + b1.w, 0.f);
    if (g == 0) {
        float4* o4 = (float4*)out;
        o4[(size_t)node * 16 + t] = v0;
        o4[(size_t)node * 16 + t + 8] = v1;
    }
}

// ---------------- aggregate v5 + fused head ----------------
__global__ __launch_bounds__(256) void k_aggregate_head(const float* __restrict__ Hs,
                                                        const int* __restrict__ row_start,
                                                        const int* __restrict__ csr_src,
                                                        const float* __restrict__ dis,
                                                        const float* __restrict__ bias,
                                                        const float* __restrict__ Wl,
                                                        const float* __restrict__ bl, int N,
                                                        float* __restrict__ out) {
    const float4* Hs4 = (const float4*)Hs;
    int wave = threadIdx.x >> 6, lane = threadIdx.x & 63;
    int node = blockIdx.x * 4 + wave;
    if (node >= N) return;
    int t = lane & 7, g = lane >> 3;
    float4 a0 = make_float4(0.f, 0.f, 0.f, 0.f);
    float4 a1 = a0;
    if (g == 0) {
        a0 = Hs4[(size_t)node * 16 + t];
        a1 = Hs4[(size_t)node * 16 + t + 8];
    }
    int e0 = row_start[node], e1 = row_start[node + 1];
    for (int eb = e0; eb < e1; eb += 64) {
        int cnt = min(64, e1 - eb);
        int sv = (eb + lane < e1) ? csr_src[eb + lane] : 0;
        for (int jb = 0; jb < cnt; jb += 16) {
            int i0 = jb + g, i1 = jb + 8 + g;
            int s0 = __shfl(sv, i0 < cnt ? i0 : 0);
            int s1 = __shfl(sv, i1 < cnt ? i1 : 0);
            size_t b0 = (size_t)s0 * 16, b1 = (size_t)s1 * 16;
            float4 z00 = Hs4[b0 + t];
            float4 z01 = Hs4[b0 + t + 8];
            float4 z10 = Hs4[b1 + t];
            float4 z11 = Hs4[b1 + t + 8];
            if (i0 < cnt) {
                a0.x += z00.x; a0.y += z00.y; a0.z += z00.z; a0.w += z00.w;
                a1.x += z01.x; a1.y += z01.y; a1.z += z01.z; a1.w += z01.w;
            }
            if (i1 < cnt) {
                a0.x += z10.x; a0.y += z10.y; a0.z += z10.z; a0.w += z10.w;
                a1.x += z11.x; a1.y += z11.y; a1.z += z11.z; a1.w += z11.w;
            }
        }
    }
#pragma unroll
    for (int off = 8; off < 64; off <<= 1) {
        a0.x += __shfl_xor(a0.x, off); a0.y += __shfl_xor(a0.y, off);
        a0.z += __shfl_xor(a0.z, off); a0.w += __shfl_xor(a0.w, off);
        a1.x += __shfl_xor(a1.x, off); a1.y += __shfl_xor(a1.y, off);
        a1.z += __shfl_xor(a1.z, off); a1.w += __shfl_xor(a1.w, off);
    }
    float sc = dis[node];
    const float4* b4 = (const float4*)bias;
    float4 b0 = b4[t], b1 = b4[t + 8];
    float4 v0, v1;
    v0.x = fmaxf(a0.x * sc + b0.x, 0.f); v0.y = fmaxf(a0.y * sc + b0.y, 0.f);
    v0.z = fmaxf(a0.z * sc + b0.z, 0.f); v0.w = fmaxf(a0.w * sc + b0.w, 0.f);
    v1.x = fmaxf(a1.x * sc + b1.x, 0.f); v1.y = fmaxf(a1.y * sc + b1.y, 0.f);
    v1.z = fmaxf(a1.z * sc + b1.z, 0.f); v1.w = fmaxf(a1.w * sc + b1.w, 0.f);
    // head: v0 covers channels 4t..4t+3 ; v1 covers 32+4t..35+4t
    int c0 = 4 * t, c1 = 32 + 4 * t;
    float p0 = v0.x * Wl[(c0 + 0) * 2] + v0.y * Wl[(c0 + 1) * 2] +
               v0.z * Wl[(c0 + 2) * 2] + v0.w * Wl[(c0 + 3) * 2] +
               v1.x * Wl[(c1 + 0) * 2] + v1.y * Wl[(c1 + 1) * 2] +
               v1.z * Wl[(c1 + 2) * 2] + v1.w * Wl[(c1 + 3) * 2];
    float p1 = v0.x * Wl[(c0 + 0) * 2 + 1] + v0.y * Wl[(c0 + 1) * 2 + 1] +
               v0.z * Wl[(c0 + 2) * 2 + 1] + v0.w * Wl[(c0 + 3) * 2 + 1] +
               v1.x * Wl[(c1 + 0) * 2 + 1] + v1.y * Wl[(c1 + 1) * 2 + 1] +
               v1.z * Wl[(c1 + 2) * 2 + 1] + v1.w * Wl[(c1 + 3) * 2 + 1];
    // reduce over t (lane bits 0-2); all g-copies identical after the xor reduce above
    p0 += __shfl_xor(p0, 1); p1 += __shfl_xor(p1, 1);
    p0 += __shfl_xor(p0, 2); p1 += __shfl_xor(p1, 2);
    p0 += __shfl_xor(p0, 4); p1 += __shfl_xor(p1, 4);
    if (lane == 0) {
        out[node * 2 + 0] = p0 + bl[0];
        out[node * 2 + 1] = p1 + bl[1];
    }
}

extern "C" void kernel_launch(void* const* d_in, const int* in_sizes, int n_in,
                              void* d_out, int out_size, void* d_ws, size_t ws_size,
                              hipStream_t stream) {
    const float* x  = (const float*)d_in[0];
    const int*   ei = (const int*)d_in[1];
    const float* W1 = (const float*)d_in[2];
    const float* b1 = (const float*)d_in[3];
    const float* W2 = (const float*)d_in[4];
    const float* b2 = (const float*)d_in[5];
    const float* Wl = (const float*)d_in[6];
    const float* bl = (const float*)d_in[7];

    const int N = in_sizes[0] / IN_DIM;   // 50000 (< 65536 required by packing)
    const int E = in_sizes[1] / 2;        // 800000
    const int* src = ei;
    const int* dst = ei + E;

    char* ws = (char*)d_ws;
    size_t off = 0;
    auto alloc = [&](size_t bytes) -> void* {
        void* p = ws + off;
        off = (off + bytes + 255) & ~(size_t)255;
        return p;
    };
    int*   bcnt      = (int*)alloc(256 * 4);
    int*   bbase     = (int*)alloc(257 * 4);
    int*   gcur      = (int*)alloc(256 * 4);
    int*   row_start = (int*)alloc(((size_t)N + 1) * 4);
    float* dis       = (float*)alloc((size_t)N * 4);
    int*   csr_src   = (int*)alloc((size_t)E * 4);
    float* bufA      = (float*)alloc((size_t)N * HID * 4);
    float* bufB      = (float*)alloc((size_t)N * HID * 4);
    unsigned* ebuf   = (unsigned*)bufA;  // alias: dead before first GEMM

    hipMemsetAsync(bcnt, 0, 256 * 4, stream);

    int eblk = (E + 4095) / 4096;  // 196
    int nb = (N + 255) / 256;      // 196
    k_bin_count<<<eblk, 256, 0, stream>>>(dst, E, bcnt);
    k_bucket_scan<<<1, 256, 0, stream>>>(bcnt, bbase, gcur, row_start, N, E);
    k_bin_scatter<<<eblk, 512, 0, stream>>>(src, dst, E, bbase, gcur, ebuf);
    k_bin_sort<<<nb, 512, 0, stream>>>(ebuf, bbase, N, E, row_start, dis, csr_src);

    int gblk = (N + 63) / 64;
    int nblk = (N + 3) / 4;
    k_gemm_scale<IN_DIM><<<gblk, 256, 0, stream>>>(x, W1, dis, N, bufA);
    k_aggregate<<<nblk, 256, 0, stream>>>(bufA, row_start, csr_src, dis, b1, N, bufB);
    k_gemm_scale<HID><<<gblk, 256, 0, stream>>>(bufB, W2, dis, N, bufA);
    k_aggregate_head<<<nblk, 256, 0, stream>>>(bufA, row_start, csr_src, dis, b2, Wl, bl, N,
                                               (float*)d_out);
}